// Round 8
// baseline (20856.944 us; speedup 1.0000x reference)
//
#include <hip/hip_runtime.h>
#include <hip/hip_bf16.h>

typedef __attribute__((ext_vector_type(8))) short bf16x8;
typedef __attribute__((ext_vector_type(4))) float f32x4;
typedef unsigned int u32t;

#define S_LEN 2048
#define BATCH 64
#define IDIM 256
#define HDIM 512
#define KDIM 768
#define ODIM 512
#define NGRP 4    // groups = XCDs 0..3, 16 batch rows each
#define NSLOT 16  // blocks per group, each owns 32 h-cols
#define LDX 264   // x slab row stride (shorts)
#define LDH 520   // h slab row stride (shorts)
#define XSLAB (16 * LDX)  // shorts per x slab
#define EP_PAD 32         // ints per private epoch line (128B)
#define POLL_CAP (1 << 16)

// producer LDS map (bytes)
#define OFF_H 16896               // xsl 2*16*LDX*2
#define OFF_PRE 33536             // hsl 16*LDH*2 = 16640
#define OFF_BIAS 41984            // pre 4*16*33*4 = 8448
#define SMEM_BYTES 98304          // force 1 block/CU (placement determinism)

__device__ __forceinline__ unsigned short f2b(float f) {
  __hip_bfloat16 h = __float2bfloat16(f);
  return __builtin_bit_cast(unsigned short, h);
}
__device__ __forceinline__ float sigmoidf_(float x) { return 1.0f / (1.0f + __expf(-x)); }
__device__ __forceinline__ float tanhf_(float x) { return 1.0f - 2.0f / (1.0f + __expf(2.0f * x)); }

__device__ __forceinline__ bf16x8 cvt8(float4 v0, float4 v1) {
  bf16x8 b;
  b[0] = (short)f2b(v0.x); b[1] = (short)f2b(v0.y);
  b[2] = (short)f2b(v0.z); b[3] = (short)f2b(v0.w);
  b[4] = (short)f2b(v1.x); b[5] = (short)f2b(v1.y);
  b[6] = (short)f2b(v1.z); b[7] = (short)f2b(v1.w);
  return b;
}

// Fresh L2 read: atomics always execute at the XCD L2 (no L0 RMW path).
// Opaque addend stops LLVM turning fetch_add(p,0) into a cacheable load.
// (Validated on HW in round 6: cross-CU flag reads via this never stale.)
__device__ __forceinline__ int l2_read(int* p) {
  int z = 0;
  asm volatile("" : "+v"(z));
  return __hip_atomic_fetch_add(p, z, __ATOMIC_RELAXED, __HIP_MEMORY_SCOPE_WORKGROUP);
}

__global__ void lstm_init(const float* __restrict__ wh2o,
                          __hip_bfloat16* __restrict__ wh2o_bf,
                          __hip_bfloat16* __restrict__ h_all,
                          int* __restrict__ ctrl) {
  int idx = blockIdx.x * 256 + threadIdx.x;
  if (idx < ODIM * HDIM) wh2o_bf[idx] = __float2bfloat16(wh2o[idx]);
  if (idx < BATCH * HDIM) h_all[idx] = __float2bfloat16(0.0f);  // h(0) = 0
  if (idx < 16384) ctrl[idx] = 0;  // cnt + epoch + per-group stepcnt (64KB)
}

// ===== persistent recurrence: 4 XCD-local groups, releaser-pattern sync =====
__global__ __launch_bounds__(512) void lstm_recur(
    const float* __restrict__ x,
    const float* __restrict__ Wi, const float* __restrict__ bi,
    const float* __restrict__ Wf, const float* __restrict__ bfp,
    const float* __restrict__ Wg, const float* __restrict__ bgp,
    const float* __restrict__ Wo, const float* __restrict__ bop,
    __hip_bfloat16* __restrict__ h_all, int* __restrict__ epoch,
    int* __restrict__ stepcnt, int* __restrict__ cnt) {
  extern __shared__ char smem[];
  __shared__ int sel[2];
  const int tid = threadIdx.x;
  const int lane = tid & 63;
  const int wave = tid >> 6;

  if (tid == 0) {
    unsigned xcd;
    asm("s_getreg_b32 %0, hwreg(HW_REG_XCC_ID)" : "=s"(xcd));
    sel[0] = (int)(xcd & 7);
    sel[1] = atomicAdd(&cnt[(xcd & 7) * 16], 1);  // one-time, device scope
  }
  __syncthreads();
  const int g = sel[0];
  const int s = sel[1];
  if (g >= NGRP || s >= NSLOT) return;  // XCDs 4-7 + surplus blocks idle

  short* xsl = (short*)smem;                // [2][16][LDX] bf16
  short* hsl = (short*)(smem + OFF_H);      // [16][LDH] bf16
  float* pre = (float*)(smem + OFF_PRE);    // [4][16][33] preacts
  float* blds = (float*)(smem + OFF_BIAS);  // [4][32]

  const int ct = wave & 3;   // gate
  const int ch = wave >> 2;  // col half (16 cols)
  const int a_r = lane & 15;          // A row / B col selector
  const int ksub = (lane >> 4) * 8;   // K sub-offset

  // --- prologue: weight fragments fp32 -> bf16 registers (full K per wave) ---
  const float* wsrc = (ct == 0) ? Wi : (ct == 1) ? Wf : (ct == 2) ? Wg : Wo;
  const float* wrow = wsrc + (size_t)(s * 32 + ch * 16 + a_r) * KDIM;
  bf16x8 bfx[8], bfh[16];
#pragma unroll
  for (int kk = 0; kk < 8; ++kk) {
    int k0 = kk * 32 + ksub;
    bfx[kk] = cvt8(*(const float4*)(wrow + k0), *(const float4*)(wrow + k0 + 4));
  }
#pragma unroll
  for (int kk = 0; kk < 16; ++kk) {
    int k0 = IDIM + kk * 32 + ksub;
    bfh[kk] = cvt8(*(const float4*)(wrow + k0), *(const float4*)(wrow + k0 + 4));
  }
  if (tid < 128) {
    int gate = tid >> 5;
    const float* bsrc = (gate == 0) ? bi : (gate == 1) ? bfp : (gate == 2) ? bgp : bop;
    blds[tid] = bsrc[s * 32 + (tid & 31)];
  }

  // x pipeline: 2-step register lookahead
  float4 rx[2];
  auto ldx = [&](int t) {
    const float4* xs = (const float4*)(x + ((size_t)t * BATCH + g * 16) * IDIM);
    rx[0] = xs[tid];
    rx[1] = xs[tid + 512];
  };
  auto stx = [&](int par) {
#pragma unroll
    for (int j = 0; j < 2; ++j) {
      int i = tid + j * 512;
      int r = i >> 6, k4 = i & 63;
      float4 v = rx[j];
      ushort4 u;
      u.x = f2b(v.x); u.y = f2b(v.y); u.z = f2b(v.z); u.w = f2b(v.w);
      *(ushort4*)&xsl[par * XSLAB + r * LDX + k4 * 4] = u;
    }
  };

  // bootstrap: x(0) -> slab0 ; x(1) -> regs
  ldx(0);
  stx(0);
  ldx(1);

  float cst = 0.0f;              // c state: one (row,col) pair per thread
  const int gr = tid >> 5;       // gate row 0..15
  const int gc = tid & 31;       // gate col 0..31
  int* myep = epoch + (g * NSLOT + s) * EP_PAD;
  int* gep = epoch + g * NSLOT * EP_PAD;
  int* gstep = stepcnt + g * S_LEN;  // PER-GROUP arrival counters (R7 bugfix)

  for (int t = 0; t < S_LEN; ++t) {
    // --- A: certify h(t) group-wide (releaser pattern, private poll lines) ---
    if (wave == 0) {
      int old = 0;
      if (lane == 0)
        old = __hip_atomic_fetch_add(&gstep[t], 1, __ATOMIC_RELAXED,
                                     __HIP_MEMORY_SCOPE_WORKGROUP);
      old = __shfl(old, 0);
      if (old == NSLOT - 1 && lane < NSLOT)
        __hip_atomic_store(gep + lane * EP_PAD, t, __ATOMIC_RELAXED,
                           __HIP_MEMORY_SCOPE_WORKGROUP);
      for (int it = 0; it < POLL_CAP; ++it) {
        if (l2_read(myep) >= t) break;
        __builtin_amdgcn_s_sleep(1);
      }
    }
    __syncthreads();
    // --- B: stage h(t) -> LDS ; x(t+1) regs -> LDS ; issue x(t+2) loads ---
    stx((t + 1) & 1);  // consumes rx = x(t+1)
    {
      const short* hs = (const short*)h_all + ((size_t)t * BATCH + g * 16) * HDIM;
      int r = tid >> 5, c16 = tid & 31;
      const short* sp = hs + r * HDIM + c16 * 16;
      bf16x8 v0 = *(const bf16x8*)sp;
      bf16x8 v1 = *(const bf16x8*)(sp + 8);
      short* dp = &hsl[r * LDH + c16 * 16];
      *(bf16x8*)dp = v0;
      *(bf16x8*)(dp + 8) = v1;
    }
    ldx((t + 2 < S_LEN) ? t + 2 : S_LEN - 1);  // overwrites rx (after stx)
    __syncthreads();
    // --- C: full gate GEMM (K=768) : 8 x-MFMA + 16 h-MFMA, 4 chains ---
    {
      const short* acx = &xsl[(t & 1) * XSLAB + a_r * LDX + ksub];
      const short* ach = &hsl[a_r * LDH + ksub];
      f32x4 c0 = {}, c1 = {}, c2 = {}, c3 = {};
#pragma unroll
      for (int kk = 0; kk < 8; kk += 2) {
        c0 = __builtin_amdgcn_mfma_f32_16x16x32_bf16(*(const bf16x8*)(acx + kk * 32),
                                                     bfx[kk], c0, 0, 0, 0);
        c1 = __builtin_amdgcn_mfma_f32_16x16x32_bf16(*(const bf16x8*)(acx + kk * 32 + 32),
                                                     bfx[kk + 1], c1, 0, 0, 0);
      }
#pragma unroll
      for (int kk = 0; kk < 16; kk += 2) {
        c2 = __builtin_amdgcn_mfma_f32_16x16x32_bf16(*(const bf16x8*)(ach + kk * 32),
                                                     bfh[kk], c2, 0, 0, 0);
        c3 = __builtin_amdgcn_mfma_f32_16x16x32_bf16(*(const bf16x8*)(ach + kk * 32 + 32),
                                                     bfh[kk + 1], c3, 0, 0, 0);
      }
      const int rb = (lane >> 4) * 4;
      const int col = ch * 16 + a_r;
#pragma unroll
      for (int j = 0; j < 4; ++j)
        pre[(ct * 16 + rb + j) * 33 + col] = c0[j] + c1[j] + c2[j] + c3[j];
    }
    __syncthreads();
    // --- D: gates + state update + publish h(t+1) (WT stores -> L2) ---
    {
      float pi = blds[gc] + pre[(0 * 16 + gr) * 33 + gc];
      float pf = blds[32 + gc] + pre[(1 * 16 + gr) * 33 + gc];
      float pg = blds[64 + gc] + pre[(2 * 16 + gr) * 33 + gc];
      float po = blds[96 + gc] + pre[(3 * 16 + gr) * 33 + gc];
      float ig = sigmoidf_(pi), fg = sigmoidf_(pf), gv = tanhf_(pg), og = sigmoidf_(po);
      cst = fg * cst + ig * gv;
      float hv = og * tanhf_(cst);
      float hv2 = __shfl_xor(hv, 1);
      if (!(gc & 1)) {
        u32t hw = (u32t)f2b(hv) | ((u32t)f2b(hv2) << 16);
        u32t* dst = (u32t*)((short*)h_all +
                            ((size_t)(t + 1) * BATCH + g * 16 + gr) * HDIM + s * 32 + gc);
        *dst = hw;
      }
    }
    asm volatile("s_waitcnt vmcnt(0)" ::: "memory");  // h(t+1) acked at L2
    __syncthreads();
  }
}

// ===== output projection + log-softmax: massively parallel, after the scan =====
__global__ __launch_bounds__(256) void lstm_out(
    const __hip_bfloat16* __restrict__ h_all,
    const __hip_bfloat16* __restrict__ wh2o_bf, const float* __restrict__ bh2o,
    float* __restrict__ out) {
  const int t = blockIdx.x;
  const int tid = threadIdx.x;
  const int lane = tid & 63;
  const int wave = tid >> 6;
  const int r0 = wave * 16;
  const short* abase = (const short*)h_all +
                       ((size_t)(t + 1) * BATCH + r0 + (lane & 15)) * HDIM + (lane >> 4) * 8;
  const short* bbase = (const short*)wh2o_bf + (size_t)(lane & 15) * HDIM + (lane >> 4) * 8;
  f32x4 acc[32];
  f32x4 zero = {0.f, 0.f, 0.f, 0.f};
#pragma unroll
  for (int n = 0; n < 32; ++n) acc[n] = zero;
  for (int kk = 0; kk < 16; ++kk) {
    bf16x8 a = *(const bf16x8*)(abase + kk * 32);
#pragma unroll
    for (int n = 0; n < 32; ++n) {
      bf16x8 b = *(const bf16x8*)(bbase + (size_t)n * 16 * HDIM + kk * 32);
      acc[n] = __builtin_amdgcn_mfma_f32_16x16x32_bf16(a, b, acc[n], 0, 0, 0);
    }
  }
  float mx[4] = {-3.0e38f, -3.0e38f, -3.0e38f, -3.0e38f};
#pragma unroll
  for (int n = 0; n < 32; ++n) {
    float bn = bh2o[n * 16 + (lane & 15)];
#pragma unroll
    for (int j = 0; j < 4; ++j) {
      acc[n][j] += bn;
      mx[j] = fmaxf(mx[j], acc[n][j]);
    }
  }
#pragma unroll
  for (int j = 0; j < 4; ++j) {
    mx[j] = fmaxf(mx[j], __shfl_xor(mx[j], 1));
    mx[j] = fmaxf(mx[j], __shfl_xor(mx[j], 2));
    mx[j] = fmaxf(mx[j], __shfl_xor(mx[j], 4));
    mx[j] = fmaxf(mx[j], __shfl_xor(mx[j], 8));
  }
  float sm[4] = {0.f, 0.f, 0.f, 0.f};
#pragma unroll
  for (int n = 0; n < 32; ++n) {
#pragma unroll
    for (int j = 0; j < 4; ++j) sm[j] += __expf(acc[n][j] - mx[j]);
  }
#pragma unroll
  for (int j = 0; j < 4; ++j) {
    sm[j] += __shfl_xor(sm[j], 1);
    sm[j] += __shfl_xor(sm[j], 2);
    sm[j] += __shfl_xor(sm[j], 4);
    sm[j] += __shfl_xor(sm[j], 8);
  }
  float ls[4];
#pragma unroll
  for (int j = 0; j < 4; ++j) ls[j] = mx[j] + __logf(sm[j]);
  float* ob = out + (size_t)t * BATCH * ODIM;
#pragma unroll
  for (int n = 0; n < 32; ++n) {
#pragma unroll
    for (int j = 0; j < 4; ++j) {
      int row = r0 + (lane >> 4) * 4 + j;
      ob[(size_t)row * ODIM + n * 16 + (lane & 15)] = acc[n][j] - ls[j];
    }
  }
}

extern "C" void kernel_launch(void* const* d_in, const int* in_sizes, int n_in,
                              void* d_out, int out_size, void* d_ws, size_t ws_size,
                              hipStream_t stream) {
  const float* x = (const float*)d_in[0];
  const float* Wi = (const float*)d_in[1];
  const float* bi = (const float*)d_in[2];
  const float* Wf = (const float*)d_in[3];
  const float* bf = (const float*)d_in[4];
  const float* Wg = (const float*)d_in[5];
  const float* bg = (const float*)d_in[6];
  const float* Wo = (const float*)d_in[7];
  const float* bo = (const float*)d_in[8];
  const float* Wh2o = (const float*)d_in[9];
  const float* bh2o = (const float*)d_in[10];

  char* ws = (char*)d_ws;
  int* cnt = (int*)ws;                       // 8 XCD counters (padded)
  int* epoch = (int*)(ws + 2048);            // [NGRP][NSLOT][EP_PAD] private lines
  int* stepcnt = (int*)(ws + 16384);         // [NGRP][S_LEN] arrival counters
  __hip_bfloat16* h_all = (__hip_bfloat16*)(ws + 65536);  // [S+1][64][512]
  size_t h_all_b = (size_t)(S_LEN + 1) * BATCH * HDIM * 2;
  __hip_bfloat16* wh2o_bf = (__hip_bfloat16*)(ws + 65536 + h_all_b);
  size_t needed = 65536 + h_all_b + (size_t)ODIM * HDIM * 2;
  if (ws_size < needed || n_in < 11) return;

  hipFuncSetAttribute((const void*)lstm_recur,
                      hipFuncAttributeMaxDynamicSharedMemorySize, SMEM_BYTES);

  lstm_init<<<1024, 256, 0, stream>>>(Wh2o, wh2o_bf, h_all, (int*)ws);
  lstm_recur<<<256, 512, SMEM_BYTES, stream>>>(x, Wi, bi, Wf, bf, Wg, bg, Wo, bo,
                                               h_all, epoch, stepcnt, cnt);
  lstm_out<<<S_LEN, 256, 0, stream>>>(h_all, wh2o_bf, bh2o, (float*)d_out);
}

// Round 10
// 17308.649 us; speedup vs baseline: 1.2050x; 1.2050x over previous
//
#include <hip/hip_runtime.h>
#include <hip/hip_bf16.h>

typedef __attribute__((ext_vector_type(8))) short bf16x8;
typedef __attribute__((ext_vector_type(4))) float f32x4;
typedef unsigned int u32t;

#define S_LEN 2048
#define BATCH 64
#define IDIM 256
#define HDIM 512
#define KDIM 768
#define ODIM 512
#define NGRP 4    // groups = XCDs 0..3, 16 batch rows each
#define NSLOT 16  // blocks per group, each owns 32 h-cols
#define LDX 264   // x slab row stride (shorts)
#define LDH 520   // h slab row stride (shorts)
#define XSLAB (16 * LDX)  // shorts per x slab
#define EP_PAD 32         // ints per private epoch line (128B)
#define POLL_CAP (1 << 16)

// producer LDS map (bytes)
#define OFF_H 16896               // xsl 2*16*LDX*2
#define OFF_PRE 33536             // hsl 16*LDH*2 = 16640
#define OFF_BIAS 41984            // pre 4*16*33*4 = 8448
#define SMEM_BYTES 98304          // force 1 block/CU (placement determinism)

__device__ __forceinline__ unsigned short f2b(float f) {
  __hip_bfloat16 h = __float2bfloat16(f);
  return __builtin_bit_cast(unsigned short, h);
}
__device__ __forceinline__ float sigmoidf_(float x) { return 1.0f / (1.0f + __expf(-x)); }
__device__ __forceinline__ float tanhf_(float x) { return 1.0f - 2.0f / (1.0f + __expf(2.0f * x)); }

__device__ __forceinline__ bf16x8 cvt8(float4 v0, float4 v1) {
  bf16x8 b;
  b[0] = (short)f2b(v0.x); b[1] = (short)f2b(v0.y);
  b[2] = (short)f2b(v0.z); b[3] = (short)f2b(v0.w);
  b[4] = (short)f2b(v1.x); b[5] = (short)f2b(v1.y);
  b[6] = (short)f2b(v1.z); b[7] = (short)f2b(v1.w);
  return b;
}

// Fresh L2 read: atomics always execute at the XCD L2 (no L0 RMW path).
// Opaque addend stops LLVM turning fetch_add(p,0) into a cacheable load.
// (HW-validated in rounds 6/8: cross-CU flag reads via this are never stale.)
__device__ __forceinline__ int l2_read(int* p) {
  int z = 0;
  asm volatile("" : "+v"(z));
  return __hip_atomic_fetch_add(p, z, __ATOMIC_RELAXED, __HIP_MEMORY_SCOPE_WORKGROUP);
}

__global__ void lstm_init(const float* __restrict__ wh2o,
                          __hip_bfloat16* __restrict__ wh2o_bf,
                          __hip_bfloat16* __restrict__ h_all,
                          int* __restrict__ ctrl) {
  int idx = blockIdx.x * 256 + threadIdx.x;
  if (idx < ODIM * HDIM) wh2o_bf[idx] = __float2bfloat16(wh2o[idx]);
  if (idx < BATCH * HDIM) h_all[idx] = __float2bfloat16(0.0f);  // h(0) = 0
  if (idx < 16384) ctrl[idx] = 0;  // cnt + epoch + per-group stepcnt (64KB)
}

// ===== persistent recurrence: 4 XCD-local groups, releaser-pattern sync =====
__global__ __launch_bounds__(512) void lstm_recur(
    const float* __restrict__ x,
    const float* __restrict__ Wi, const float* __restrict__ bi,
    const float* __restrict__ Wf, const float* __restrict__ bfp,
    const float* __restrict__ Wg, const float* __restrict__ bgp,
    const float* __restrict__ Wo, const float* __restrict__ bop,
    __hip_bfloat16* __restrict__ h_all, int* __restrict__ epoch,
    int* __restrict__ stepcnt, int* __restrict__ cnt) {
  extern __shared__ char smem[];
  __shared__ int sel[2];
  const int tid = threadIdx.x;
  const int lane = tid & 63;
  const int wave = tid >> 6;

  if (tid == 0) {
    unsigned xcd;
    asm("s_getreg_b32 %0, hwreg(HW_REG_XCC_ID)" : "=s"(xcd));
    sel[0] = (int)(xcd & 7);
    sel[1] = atomicAdd(&cnt[(xcd & 7) * 16], 1);  // one-time, device scope
  }
  __syncthreads();
  const int g = sel[0];
  const int s = sel[1];
  if (g >= NGRP || s >= NSLOT) return;  // XCDs 4-7 + surplus blocks idle

  short* xsl = (short*)smem;                // [2][16][LDX] bf16
  short* hsl = (short*)(smem + OFF_H);      // [16][LDH] bf16
  float* pre = (float*)(smem + OFF_PRE);    // [4][16][33] preacts
  float* blds = (float*)(smem + OFF_BIAS);  // [4][32]

  const int ct = wave & 3;   // gate
  const int ch = wave >> 2;  // col half (16 cols)
  const int a_r = lane & 15;          // A row / B col selector
  const int ksub = (lane >> 4) * 8;   // K sub-offset

  // --- prologue: weight fragments fp32 -> bf16 registers (full K per wave) ---
  const float* wsrc = (ct == 0) ? Wi : (ct == 1) ? Wf : (ct == 2) ? Wg : Wo;
  const float* wrow = wsrc + (size_t)(s * 32 + ch * 16 + a_r) * KDIM;
  bf16x8 bfx[8], bfh[16];
#pragma unroll
  for (int kk = 0; kk < 8; ++kk) {
    int k0 = kk * 32 + ksub;
    bfx[kk] = cvt8(*(const float4*)(wrow + k0), *(const float4*)(wrow + k0 + 4));
  }
#pragma unroll
  for (int kk = 0; kk < 16; ++kk) {
    int k0 = IDIM + kk * 32 + ksub;
    bfh[kk] = cvt8(*(const float4*)(wrow + k0), *(const float4*)(wrow + k0 + 4));
  }
  if (tid < 128) {
    int gate = tid >> 5;
    const float* bsrc = (gate == 0) ? bi : (gate == 1) ? bfp : (gate == 2) ? bgp : bop;
    blds[tid] = bsrc[s * 32 + (tid & 31)];
  }

  // x pipeline: 2-step register lookahead
  float4 rx[2];
  auto ldx = [&](int t) {
    const float4* xs = (const float4*)(x + ((size_t)t * BATCH + g * 16) * IDIM);
    rx[0] = xs[tid];
    rx[1] = xs[tid + 512];
  };
  auto stx = [&](int par) {
#pragma unroll
    for (int j = 0; j < 2; ++j) {
      int i = tid + j * 512;
      int r = i >> 6, k4 = i & 63;
      float4 v = rx[j];
      ushort4 u;
      u.x = f2b(v.x); u.y = f2b(v.y); u.z = f2b(v.z); u.w = f2b(v.w);
      *(ushort4*)&xsl[par * XSLAB + r * LDX + k4 * 4] = u;
    }
  };

  // bootstrap: x(0) -> slab0 ; x(1) -> regs
  ldx(0);
  stx(0);
  ldx(1);

  float cst = 0.0f;              // c state: one (row,col) pair per thread
  const int gr = tid >> 5;       // gate row 0..15
  const int gc = tid & 31;       // gate col 0..31
  int* myep = epoch + (g * NSLOT + s) * EP_PAD;
  int* gep = epoch + g * NSLOT * EP_PAD;
  int* gstep = stepcnt + g * S_LEN;  // per-group arrival counters

  for (int t = 0; t < S_LEN; ++t) {
    // --- A: certify h(t) group-wide. Arrival: ONE RMW by lane 0. Release:
    //        one parallel 16-lane store. Poll: lane 0 only, private line,
    //        zero cross-block contention. Releaser skips its own poll. ---
    if (wave == 0) {
      int old = 0;
      if (lane == 0)
        old = __hip_atomic_fetch_add(&gstep[t], 1, __ATOMIC_RELAXED,
                                     __HIP_MEMORY_SCOPE_WORKGROUP);
      old = __shfl(old, 0);
      if (old == NSLOT - 1) {
        if (lane < NSLOT)
          __hip_atomic_store(gep + lane * EP_PAD, t, __ATOMIC_RELAXED,
                             __HIP_MEMORY_SCOPE_WORKGROUP);
      } else if (lane == 0) {
        for (int it = 0; it < POLL_CAP; ++it) {
          if (l2_read(myep) >= t) break;
        }
      }
    }
    __syncthreads();
    // --- B: x(t+1) regs -> LDS ; stage h(t) -> LDS ---
    stx((t + 1) & 1);  // consumes rx = x(t+1)
    {
      const short* hs = (const short*)h_all + ((size_t)t * BATCH + g * 16) * HDIM;
      int r = tid >> 5, c16 = tid & 31;
      const short* sp = hs + r * HDIM + c16 * 16;
      bf16x8 v0 = *(const bf16x8*)sp;
      bf16x8 v1 = *(const bf16x8*)(sp + 8);
      short* dp = &hsl[r * LDH + c16 * 16];
      *(bf16x8*)dp = v0;
      *(bf16x8*)(dp + 8) = v1;
    }
    __syncthreads();
    // --- C: full gate GEMM (K=768) : 8 x-MFMA + 16 h-MFMA, 4 chains ---
    {
      const short* acx = &xsl[(t & 1) * XSLAB + a_r * LDX + ksub];
      const short* ach = &hsl[a_r * LDH + ksub];
      f32x4 c0 = {}, c1 = {}, c2 = {}, c3 = {};
#pragma unroll
      for (int kk = 0; kk < 8; kk += 2) {
        c0 = __builtin_amdgcn_mfma_f32_16x16x32_bf16(*(const bf16x8*)(acx + kk * 32),
                                                     bfx[kk], c0, 0, 0, 0);
        c1 = __builtin_amdgcn_mfma_f32_16x16x32_bf16(*(const bf16x8*)(acx + kk * 32 + 32),
                                                     bfx[kk + 1], c1, 0, 0, 0);
      }
#pragma unroll
      for (int kk = 0; kk < 16; kk += 2) {
        c2 = __builtin_amdgcn_mfma_f32_16x16x32_bf16(*(const bf16x8*)(ach + kk * 32),
                                                     bfh[kk], c2, 0, 0, 0);
        c3 = __builtin_amdgcn_mfma_f32_16x16x32_bf16(*(const bf16x8*)(ach + kk * 32 + 32),
                                                     bfh[kk + 1], c3, 0, 0, 0);
      }
      const int rb = (lane >> 4) * 4;
      const int col = ch * 16 + a_r;
#pragma unroll
      for (int j = 0; j < 4; ++j)
        pre[(ct * 16 + rb + j) * 33 + col] = c0[j] + c1[j] + c2[j] + c3[j];
    }
    __syncthreads();
    // --- D: gates + state update + publish h(t+1) (WT stores -> L2).
    //        ALL 512 threads participate: gr = tid>>5 covers rows 0..15. ---
    {
      float pi = blds[gc] + pre[(0 * 16 + gr) * 33 + gc];
      float pf = blds[32 + gc] + pre[(1 * 16 + gr) * 33 + gc];
      float pg = blds[64 + gc] + pre[(2 * 16 + gr) * 33 + gc];
      float po = blds[96 + gc] + pre[(3 * 16 + gr) * 33 + gc];
      float ig = sigmoidf_(pi), fg = sigmoidf_(pf), gv = tanhf_(pg), og = sigmoidf_(po);
      cst = fg * cst + ig * gv;
      float hv = og * tanhf_(cst);
      float hv2 = __shfl_xor(hv, 1);
      if (!(gc & 1)) {  // R9 bug was an extra tid<256 here: halved the publish
        u32t hw = (u32t)f2b(hv) | ((u32t)f2b(hv2) << 16);
        u32t* dst = (u32t*)((short*)h_all +
                            ((size_t)(t + 1) * BATCH + g * 16 + gr) * HDIM + s * 32 + gc);
        *dst = hw;
      }
    }
    // Drain covers ONLY the h stores (stage-h loads completed in B; x loads
    // for t+2 are issued after this point so they never extend the drain).
    asm volatile("s_waitcnt vmcnt(0)" ::: "memory");  // h(t+1) acked at L2
    __syncthreads();
    // --- issue x(t+2) loads; they fly during next step's A-poll window ---
    if (t + 1 < S_LEN) ldx((t + 2 < S_LEN) ? t + 2 : S_LEN - 1);
  }
}

// ===== output projection + log-softmax: massively parallel, after the scan =====
__global__ __launch_bounds__(256) void lstm_out(
    const __hip_bfloat16* __restrict__ h_all,
    const __hip_bfloat16* __restrict__ wh2o_bf, const float* __restrict__ bh2o,
    float* __restrict__ out) {
  const int t = blockIdx.x;
  const int tid = threadIdx.x;
  const int lane = tid & 63;
  const int wave = tid >> 6;
  const int r0 = wave * 16;
  const short* abase = (const short*)h_all +
                       ((size_t)(t + 1) * BATCH + r0 + (lane & 15)) * HDIM + (lane >> 4) * 8;
  const short* bbase = (const short*)wh2o_bf + (size_t)(lane & 15) * HDIM + (lane >> 4) * 8;
  f32x4 acc[32];
  f32x4 zero = {0.f, 0.f, 0.f, 0.f};
#pragma unroll
  for (int n = 0; n < 32; ++n) acc[n] = zero;
  for (int kk = 0; kk < 16; ++kk) {
    bf16x8 a = *(const bf16x8*)(abase + kk * 32);
#pragma unroll
    for (int n = 0; n < 32; ++n) {
      bf16x8 b = *(const bf16x8*)(bbase + (size_t)n * 16 * HDIM + kk * 32);
      acc[n] = __builtin_amdgcn_mfma_f32_16x16x32_bf16(a, b, acc[n], 0, 0, 0);
    }
  }
  float mx[4] = {-3.0e38f, -3.0e38f, -3.0e38f, -3.0e38f};
#pragma unroll
  for (int n = 0; n < 32; ++n) {
    float bn = bh2o[n * 16 + (lane & 15)];
#pragma unroll
    for (int j = 0; j < 4; ++j) {
      acc[n][j] += bn;
      mx[j] = fmaxf(mx[j], acc[n][j]);
    }
  }
#pragma unroll
  for (int j = 0; j < 4; ++j) {
    mx[j] = fmaxf(mx[j], __shfl_xor(mx[j], 1));
    mx[j] = fmaxf(mx[j], __shfl_xor(mx[j], 2));
    mx[j] = fmaxf(mx[j], __shfl_xor(mx[j], 4));
    mx[j] = fmaxf(mx[j], __shfl_xor(mx[j], 8));
  }
  float sm[4] = {0.f, 0.f, 0.f, 0.f};
#pragma unroll
  for (int n = 0; n < 32; ++n) {
#pragma unroll
    for (int j = 0; j < 4; ++j) sm[j] += __expf(acc[n][j] - mx[j]);
  }
#pragma unroll
  for (int j = 0; j < 4; ++j) {
    sm[j] += __shfl_xor(sm[j], 1);
    sm[j] += __shfl_xor(sm[j], 2);
    sm[j] += __shfl_xor(sm[j], 4);
    sm[j] += __shfl_xor(sm[j], 8);
  }
  float ls[4];
#pragma unroll
  for (int j = 0; j < 4; ++j) ls[j] = mx[j] + __logf(sm[j]);
  float* ob = out + (size_t)t * BATCH * ODIM;
#pragma unroll
  for (int n = 0; n < 32; ++n) {
#pragma unroll
    for (int j = 0; j < 4; ++j) {
      int row = r0 + (lane >> 4) * 4 + j;
      ob[(size_t)row * ODIM + n * 16 + (lane & 15)] = acc[n][j] - ls[j];
    }
  }
}

extern "C" void kernel_launch(void* const* d_in, const int* in_sizes, int n_in,
                              void* d_out, int out_size, void* d_ws, size_t ws_size,
                              hipStream_t stream) {
  const float* x = (const float*)d_in[0];
  const float* Wi = (const float*)d_in[1];
  const float* bi = (const float*)d_in[2];
  const float* Wf = (const float*)d_in[3];
  const float* bf = (const float*)d_in[4];
  const float* Wg = (const float*)d_in[5];
  const float* bg = (const float*)d_in[6];
  const float* Wo = (const float*)d_in[7];
  const float* bo = (const float*)d_in[8];
  const float* Wh2o = (const float*)d_in[9];
  const float* bh2o = (const float*)d_in[10];

  char* ws = (char*)d_ws;
  int* cnt = (int*)ws;                       // 8 XCD counters (padded)
  int* epoch = (int*)(ws + 2048);            // [NGRP][NSLOT][EP_PAD] private lines
  int* stepcnt = (int*)(ws + 16384);         // [NGRP][S_LEN] arrival counters
  __hip_bfloat16* h_all = (__hip_bfloat16*)(ws + 65536);  // [S+1][64][512]
  size_t h_all_b = (size_t)(S_LEN + 1) * BATCH * HDIM * 2;
  __hip_bfloat16* wh2o_bf = (__hip_bfloat16*)(ws + 65536 + h_all_b);
  size_t needed = 65536 + h_all_b + (size_t)ODIM * HDIM * 2;
  if (ws_size < needed || n_in < 11) return;

  hipFuncSetAttribute((const void*)lstm_recur,
                      hipFuncAttributeMaxDynamicSharedMemorySize, SMEM_BYTES);

  lstm_init<<<1024, 256, 0, stream>>>(Wh2o, wh2o_bf, h_all, (int*)ws);
  lstm_recur<<<256, 512, SMEM_BYTES, stream>>>(x, Wi, bi, Wf, bf, Wg, bg, Wo, bo,
                                               h_all, epoch, stepcnt, cnt);
  lstm_out<<<S_LEN, 256, 0, stream>>>(h_all, wh2o_bf, bh2o, (float*)d_out);
}

// Round 11
// 17024.809 us; speedup vs baseline: 1.2251x; 1.0167x over previous
//
#include <hip/hip_runtime.h>
#include <hip/hip_bf16.h>

typedef __attribute__((ext_vector_type(8))) short bf16x8;
typedef __attribute__((ext_vector_type(4))) float f32x4;
typedef unsigned int u32t;

#define S_LEN 2048
#define BATCH 64
#define IDIM 256
#define HDIM 512
#define KDIM 768
#define ODIM 512
#define NGRP 4    // groups = XCDs 0..3, 16 batch rows each
#define NSLOT 16  // blocks per group, each owns 32 h-cols (8 waves x 4)
#define LDX 264   // x slab row stride (shorts)
#define LDH 520   // h slab row stride (shorts)
#define XSLAB (16 * LDX)
#define FLAG_PAD 16       // ints per flag line (64B)
#define POLL_CAP (1 << 16)

#define OFF_H 16896       // xsl [2][16][LDX]*2B
#define SMEM_BYTES 98304  // force 1 block/CU (placement determinism)

__device__ __forceinline__ unsigned short f2b(float f) {
  __hip_bfloat16 h = __float2bfloat16(f);
  return __builtin_bit_cast(unsigned short, h);
}
__device__ __forceinline__ float sigmoidf_(float x) { return 1.0f / (1.0f + __expf(-x)); }
__device__ __forceinline__ float tanhf_(float x) { return 1.0f - 2.0f / (1.0f + __expf(2.0f * x)); }

__device__ __forceinline__ bf16x8 cvt8(float4 v0, float4 v1) {
  bf16x8 b;
  b[0] = (short)f2b(v0.x); b[1] = (short)f2b(v0.y);
  b[2] = (short)f2b(v0.z); b[3] = (short)f2b(v0.w);
  b[4] = (short)f2b(v1.x); b[5] = (short)f2b(v1.y);
  b[6] = (short)f2b(v1.z); b[7] = (short)f2b(v1.w);
  return b;
}

// Fresh L2 read: atomics execute at the XCD L2 (no L0 RMW path). Opaque addend
// stops LLVM folding fetch_add(p,0) into a cacheable load. HW-validated r6/r8/r10.
__device__ __forceinline__ int l2_read(int* p) {
  int z = 0;
  asm volatile("" : "+v"(z));
  return __hip_atomic_fetch_add(p, z, __ATOMIC_RELAXED, __HIP_MEMORY_SCOPE_WORKGROUP);
}

__global__ void lstm_init(const float* __restrict__ wh2o,
                          __hip_bfloat16* __restrict__ wh2o_bf,
                          __hip_bfloat16* __restrict__ h_all,
                          int* __restrict__ ctrl) {
  int idx = blockIdx.x * 256 + threadIdx.x;
  if (idx < ODIM * HDIM) wh2o_bf[idx] = __float2bfloat16(wh2o[idx]);
  if (idx < BATCH * HDIM) h_all[idx] = __float2bfloat16(0.0f);  // h(0) = 0
  if (idx < 16384) ctrl[idx] = 0;  // cnt + flags
}

// ===== persistent recurrence: 4 XCD-local groups, direct-flag gather sync =====
__global__ __launch_bounds__(512) void lstm_recur(
    const float* __restrict__ x,
    const float* __restrict__ Wi, const float* __restrict__ bi,
    const float* __restrict__ Wf, const float* __restrict__ bfp,
    const float* __restrict__ Wg, const float* __restrict__ bgp,
    const float* __restrict__ Wo, const float* __restrict__ bop,
    __hip_bfloat16* __restrict__ h_all, int* __restrict__ flags,
    int* __restrict__ cnt) {
  extern __shared__ char smem[];
  __shared__ int sel[2];
  const int tid = threadIdx.x;
  const int lane = tid & 63;
  const int wave = tid >> 6;

  if (tid == 0) {
    unsigned xcd;
    asm("s_getreg_b32 %0, hwreg(HW_REG_XCC_ID)" : "=s"(xcd));
    sel[0] = (int)(xcd & 7);
    sel[1] = atomicAdd(&cnt[(xcd & 7) * 16], 1);  // one-time, device scope
  }
  __syncthreads();
  const int g = sel[0];
  const int s = sel[1];
  if (g >= NGRP || s >= NSLOT) return;  // XCDs 4-7 + surplus blocks idle

  short* xsl = (short*)smem;            // [2][16][LDX] bf16
  short* hsl = (short*)(smem + OFF_H);  // [16][LDH] bf16

  // Wave w's MFMA B-tile: 16 cols = {gate 0..3} x {h-col w*4+q}, full K=768.
  const int bc = lane & 15;         // B col
  const int gate = bc >> 2;         // gate of this col
  const int q = bc & 3;             // h-col within wave's 4
  const int hi8 = (lane >> 4) * 8;  // K sub-slice

  // --- prologue: weight fragments fp32 -> bf16 registers ---
  const float* wsrc = (gate == 0) ? Wi : (gate == 1) ? Wf : (gate == 2) ? Wg : Wo;
  const float* wrow = wsrc + (size_t)(s * 32 + wave * 4 + q) * KDIM;
  bf16x8 bfr[24];  // kk 0..7 = x-part (K 0..255), 8..23 = h-part (K 256..767)
#pragma unroll
  for (int kk = 0; kk < 24; ++kk) {
    int k0 = kk * 32 + hi8;
    bfr[kk] = cvt8(*(const float4*)(wrow + k0), *(const float4*)(wrow + k0 + 4));
  }
  // per-lane bias (used by owner lanes: lane&12 == 0)
  const int hc_abs = s * 32 + wave * 4 + (lane & 3);
  const float bi_r = bi[hc_abs], bf_r = bfp[hc_abs], bg_r = bgp[hc_abs], bo_r = bop[hc_abs];

  // x pipeline: 2-step register lookahead
  float4 rx[2];
  auto ldx = [&](int t) {
    const float4* xs = (const float4*)(x + ((size_t)t * BATCH + g * 16) * IDIM);
    rx[0] = xs[tid];
    rx[1] = xs[tid + 512];
  };
  auto stx = [&](int par) {
#pragma unroll
    for (int j = 0; j < 2; ++j) {
      int i = tid + j * 512;
      int r = i >> 6, k4 = i & 63;
      float4 v = rx[j];
      ushort4 u;
      u.x = f2b(v.x); u.y = f2b(v.y); u.z = f2b(v.z); u.w = f2b(v.w);
      *(ushort4*)&xsl[par * XSLAB + r * LDX + k4 * 4] = u;
    }
  };

  // bootstrap: x(0) -> slab0 -> acc ; x(1) -> regs
  ldx(0);
  stx(0);
  __syncthreads();
  f32x4 c0 = {}, c1 = {};
  {
    const short* ax = &xsl[0 * XSLAB + (lane & 15) * LDX + hi8];
#pragma unroll
    for (int kk = 0; kk < 8; kk += 2) {
      c0 = __builtin_amdgcn_mfma_f32_16x16x32_bf16(*(const bf16x8*)(ax + kk * 32),
                                                   bfr[kk], c0, 0, 0, 0);
      c1 = __builtin_amdgcn_mfma_f32_16x16x32_bf16(*(const bf16x8*)(ax + kk * 32 + 32),
                                                   bfr[kk + 1], c1, 0, 0, 0);
    }
  }
  ldx(1);

  float cst[4] = {0.f, 0.f, 0.f, 0.f};  // owner lanes: 4 rows x 1 h-col
  int* myflag = flags + (g * NSLOT + s) * FLAG_PAD;
  int* gflags = flags + g * NSLOT * FLAG_PAD;

  for (int t = 0; t < S_LEN; ++t) {
    // --- A: wave0 gathers the group's 16 flag lines (pipelined RMWs) ---
    if (wave == 0) {
      for (int it = 0; it < POLL_CAP; ++it) {
        int v = (lane < NSLOT) ? l2_read(gflags + lane * FLAG_PAD) : 0x7fffffff;
        if (__all(v >= t)) break;
      }
    }
    __syncthreads();
    // --- B: x(t+1) regs -> LDS ; stage h(t) -> LDS ---
    stx((t + 1) & 1);
    {
      const short* hs = (const short*)h_all + ((size_t)t * BATCH + g * 16) * HDIM;
      int r = tid >> 5, c16 = tid & 31;
      const short* sp = hs + r * HDIM + c16 * 16;
      bf16x8 v0 = *(const bf16x8*)sp;
      bf16x8 v1 = *(const bf16x8*)(sp + 8);
      short* dp = &hsl[r * LDH + c16 * 16];
      *(bf16x8*)dp = v0;
      *(bf16x8*)(dp + 8) = v1;
    }
    __syncthreads();
    // --- C: h-part GEMM (16 MFMA, 2 chains; x-part already in c0/c1) ---
    {
      const short* ah = &hsl[(lane & 15) * LDH + hi8];
#pragma unroll
      for (int kk = 0; kk < 16; kk += 2) {
        c0 = __builtin_amdgcn_mfma_f32_16x16x32_bf16(*(const bf16x8*)(ah + kk * 32),
                                                     bfr[8 + kk], c0, 0, 0, 0);
        c1 = __builtin_amdgcn_mfma_f32_16x16x32_bf16(*(const bf16x8*)(ah + kk * 32 + 32),
                                                     bfr[9 + kk], c1, 0, 0, 0);
      }
    }
    // --- in-wave gate combine + state update + publish (owner lanes) ---
    {
      f32x4 av;
#pragma unroll
      for (int j = 0; j < 4; ++j) av[j] = c0[j] + c1[j];
      const int row0 = (lane >> 4) * 4;  // owner's 4 batch rows
      unsigned short* hb =
          (unsigned short*)h_all + (size_t)(t + 1) * BATCH * HDIM + hc_abs;
#pragma unroll
      for (int j = 0; j < 4; ++j) {
        float iv = av[j];
        float fv = __shfl(av[j], lane + 4);
        float gv = __shfl(av[j], lane + 8);
        float ov = __shfl(av[j], lane + 12);
        if ((lane & 12) == 0) {  // owner: col = gate0 slot q
          float ig = sigmoidf_(bi_r + iv);
          float fg = sigmoidf_(bf_r + fv);
          float gg = tanhf_(bg_r + gv);
          float og = sigmoidf_(bo_r + ov);
          cst[j] = fg * cst[j] + ig * gg;
          float hv = og * tanhf_(cst[j]);
          hb[(size_t)(g * 16 + row0 + j) * HDIM] = f2b(hv);
        }
      }
    }
    asm volatile("s_waitcnt vmcnt(0)" ::: "memory");  // h(t+1) acked at L2
    __syncthreads();
    if (tid == 0)
      __hip_atomic_store(myflag, t + 1, __ATOMIC_RELAXED, __HIP_MEMORY_SCOPE_WORKGROUP);
    // --- D (shadow): x loads for t+2 ; x-part GEMM for t+1 ---
    if (t + 1 < S_LEN) {
      ldx((t + 2 < S_LEN) ? t + 2 : S_LEN - 1);
      f32x4 z = {};
      c0 = z;
      c1 = z;
      const short* ax = &xsl[((t + 1) & 1) * XSLAB + (lane & 15) * LDX + hi8];
#pragma unroll
      for (int kk = 0; kk < 8; kk += 2) {
        c0 = __builtin_amdgcn_mfma_f32_16x16x32_bf16(*(const bf16x8*)(ax + kk * 32),
                                                     bfr[kk], c0, 0, 0, 0);
        c1 = __builtin_amdgcn_mfma_f32_16x16x32_bf16(*(const bf16x8*)(ax + kk * 32 + 32),
                                                     bfr[kk + 1], c1, 0, 0, 0);
      }
    }
  }
}

// ===== output projection + log-softmax: massively parallel, after the scan =====
__global__ __launch_bounds__(256) void lstm_out(
    const __hip_bfloat16* __restrict__ h_all,
    const __hip_bfloat16* __restrict__ wh2o_bf, const float* __restrict__ bh2o,
    float* __restrict__ out) {
  const int t = blockIdx.x;
  const int tid = threadIdx.x;
  const int lane = tid & 63;
  const int wave = tid >> 6;
  const int r0 = wave * 16;
  const short* abase = (const short*)h_all +
                       ((size_t)(t + 1) * BATCH + r0 + (lane & 15)) * HDIM + (lane >> 4) * 8;
  const short* bbase = (const short*)wh2o_bf + (size_t)(lane & 15) * HDIM + (lane >> 4) * 8;
  f32x4 acc[32];
  f32x4 zero = {0.f, 0.f, 0.f, 0.f};
#pragma unroll
  for (int n = 0; n < 32; ++n) acc[n] = zero;
  for (int kk = 0; kk < 16; ++kk) {
    bf16x8 a = *(const bf16x8*)(abase + kk * 32);
#pragma unroll
    for (int n = 0; n < 32; ++n) {
      bf16x8 b = *(const bf16x8*)(bbase + (size_t)n * 16 * HDIM + kk * 32);
      acc[n] = __builtin_amdgcn_mfma_f32_16x16x32_bf16(a, b, acc[n], 0, 0, 0);
    }
  }
  float mx[4] = {-3.0e38f, -3.0e38f, -3.0e38f, -3.0e38f};
#pragma unroll
  for (int n = 0; n < 32; ++n) {
    float bn = bh2o[n * 16 + (lane & 15)];
#pragma unroll
    for (int j = 0; j < 4; ++j) {
      acc[n][j] += bn;
      mx[j] = fmaxf(mx[j], acc[n][j]);
    }
  }
#pragma unroll
  for (int j = 0; j < 4; ++j) {
    mx[j] = fmaxf(mx[j], __shfl_xor(mx[j], 1));
    mx[j] = fmaxf(mx[j], __shfl_xor(mx[j], 2));
    mx[j] = fmaxf(mx[j], __shfl_xor(mx[j], 4));
    mx[j] = fmaxf(mx[j], __shfl_xor(mx[j], 8));
  }
  float sm[4] = {0.f, 0.f, 0.f, 0.f};
#pragma unroll
  for (int n = 0; n < 32; ++n) {
#pragma unroll
    for (int j = 0; j < 4; ++j) sm[j] += __expf(acc[n][j] - mx[j]);
  }
#pragma unroll
  for (int j = 0; j < 4; ++j) {
    sm[j] += __shfl_xor(sm[j], 1);
    sm[j] += __shfl_xor(sm[j], 2);
    sm[j] += __shfl_xor(sm[j], 4);
    sm[j] += __shfl_xor(sm[j], 8);
  }
  float ls[4];
#pragma unroll
  for (int j = 0; j < 4; ++j) ls[j] = mx[j] + __logf(sm[j]);
  float* ob = out + (size_t)t * BATCH * ODIM;
#pragma unroll
  for (int n = 0; n < 32; ++n) {
#pragma unroll
    for (int j = 0; j < 4; ++j) {
      int row = r0 + (lane >> 4) * 4 + j;
      ob[(size_t)row * ODIM + n * 16 + (lane & 15)] = acc[n][j] - ls[j];
    }
  }
}

extern "C" void kernel_launch(void* const* d_in, const int* in_sizes, int n_in,
                              void* d_out, int out_size, void* d_ws, size_t ws_size,
                              hipStream_t stream) {
  const float* x = (const float*)d_in[0];
  const float* Wi = (const float*)d_in[1];
  const float* bi = (const float*)d_in[2];
  const float* Wf = (const float*)d_in[3];
  const float* bf = (const float*)d_in[4];
  const float* Wg = (const float*)d_in[5];
  const float* bg = (const float*)d_in[6];
  const float* Wo = (const float*)d_in[7];
  const float* bo = (const float*)d_in[8];
  const float* Wh2o = (const float*)d_in[9];
  const float* bh2o = (const float*)d_in[10];

  char* ws = (char*)d_ws;
  int* cnt = (int*)ws;                    // 8 XCD counters (padded)
  int* flags = (int*)(ws + 2048);         // [NGRP][NSLOT][FLAG_PAD]
  __hip_bfloat16* h_all = (__hip_bfloat16*)(ws + 65536);  // [S+1][64][512]
  size_t h_all_b = (size_t)(S_LEN + 1) * BATCH * HDIM * 2;
  __hip_bfloat16* wh2o_bf = (__hip_bfloat16*)(ws + 65536 + h_all_b);
  size_t needed = 65536 + h_all_b + (size_t)ODIM * HDIM * 2;
  if (ws_size < needed || n_in < 11) return;

  hipFuncSetAttribute((const void*)lstm_recur,
                      hipFuncAttributeMaxDynamicSharedMemorySize, SMEM_BYTES);

  lstm_init<<<1024, 256, 0, stream>>>(Wh2o, wh2o_bf, h_all, (int*)ws);
  lstm_recur<<<256, 512, SMEM_BYTES, stream>>>(x, Wi, bi, Wf, bf, Wg, bg, Wo, bo,
                                               h_all, flags, cnt);
  lstm_out<<<S_LEN, 256, 0, stream>>>(h_all, wh2o_bf, bh2o, (float*)d_out);
}

// Round 12
// 16291.132 us; speedup vs baseline: 1.2803x; 1.0450x over previous
//
#include <hip/hip_runtime.h>
#include <hip/hip_bf16.h>

typedef __attribute__((ext_vector_type(8))) short bf16x8;
typedef __attribute__((ext_vector_type(4))) float f32x4;
typedef unsigned int u32t;

#define S_LEN 2048
#define BATCH 64
#define IDIM 256
#define HDIM 512
#define KDIM 768
#define ODIM 512
#define NGRP 4    // groups = XCDs 0..3, 16 batch rows each
#define NSLOT 16  // blocks per group, each owns 32 h-cols (8 waves x 4)
#define NREP 8    // flag replicas: one per wave-slot
#define LDX 264   // x slab row stride (shorts)
#define XSLAB (16 * LDX)
#define REP_STRIDE 32     // ints per replica line (128B)
#define POLL_CAP (1 << 16)

#define SMEM_BYTES 98304  // force 1 block/CU (placement determinism)

__device__ __forceinline__ unsigned short f2b(float f) {
  __hip_bfloat16 h = __float2bfloat16(f);
  return __builtin_bit_cast(unsigned short, h);
}
__device__ __forceinline__ float sigmoidf_(float x) { return 1.0f / (1.0f + __expf(-x)); }
__device__ __forceinline__ float tanhf_(float x) { return 1.0f - 2.0f / (1.0f + __expf(2.0f * x)); }

__device__ __forceinline__ bf16x8 cvt8(float4 v0, float4 v1) {
  bf16x8 b;
  b[0] = (short)f2b(v0.x); b[1] = (short)f2b(v0.y);
  b[2] = (short)f2b(v0.z); b[3] = (short)f2b(v0.w);
  b[4] = (short)f2b(v1.x); b[5] = (short)f2b(v1.y);
  b[6] = (short)f2b(v1.z); b[7] = (short)f2b(v1.w);
  return b;
}

// Fresh L2 read: atomics execute at the XCD L2 (no L0 RMW path). Opaque addend
// stops LLVM folding fetch_add(p,0) into a cacheable load. HW-validated r6-r11.
__device__ __forceinline__ int l2_read(int* p) {
  int z = 0;
  asm volatile("" : "+v"(z));
  return __hip_atomic_fetch_add(p, z, __ATOMIC_RELAXED, __HIP_MEMORY_SCOPE_WORKGROUP);
}

__global__ void lstm_init(const float* __restrict__ wh2o,
                          __hip_bfloat16* __restrict__ wh2o_bf,
                          __hip_bfloat16* __restrict__ h_all,
                          int* __restrict__ ctrl) {
  int idx = blockIdx.x * 256 + threadIdx.x;
  if (idx < ODIM * HDIM) wh2o_bf[idx] = __float2bfloat16(wh2o[idx]);
  if (idx < BATCH * HDIM) h_all[idx] = __float2bfloat16(0.0f);  // h(0) = 0
  if (idx < 32768) ctrl[idx] = 0;  // cnt + replicated flags (128KB)
}

// ===== persistent recurrence: 4 XCD-local groups, per-wave autonomous sync =====
__global__ __launch_bounds__(512) void lstm_recur(
    const float* __restrict__ x,
    const float* __restrict__ Wi, const float* __restrict__ bi,
    const float* __restrict__ Wf, const float* __restrict__ bfp,
    const float* __restrict__ Wg, const float* __restrict__ bgp,
    const float* __restrict__ Wo, const float* __restrict__ bop,
    __hip_bfloat16* __restrict__ h_all, int* __restrict__ flags,
    int* __restrict__ cnt) {
  extern __shared__ char smem[];
  __shared__ int sel[2];
  const int tid = threadIdx.x;
  const int lane = tid & 63;
  const int wave = tid >> 6;

  if (tid == 0) {
    unsigned xcd;
    asm("s_getreg_b32 %0, hwreg(HW_REG_XCC_ID)" : "=s"(xcd));
    sel[0] = (int)(xcd & 7);
    sel[1] = atomicAdd(&cnt[(xcd & 7) * 16], 1);  // one-time, device scope
  }
  __syncthreads();
  const int g = sel[0];
  const int s = sel[1];
  if (g >= NGRP || s >= NSLOT) return;  // XCDs 4-7 + surplus blocks idle

  short* xsl = (short*)smem;  // [2][16][LDX] bf16 (only LDS use)

  // Wave's MFMA B-tile: 16 cols = {gate 0..3} x {h-col wave*4+q}, full K=768.
  const int bc = lane & 15;
  const int gate = bc >> 2;
  const int q = bc & 3;
  const int hi8 = (lane >> 4) * 8;  // K sub-slice

  // --- prologue: weight fragments fp32 -> bf16 registers ---
  const float* wsrc = (gate == 0) ? Wi : (gate == 1) ? Wf : (gate == 2) ? Wg : Wo;
  const float* wrow = wsrc + (size_t)(s * 32 + wave * 4 + q) * KDIM;
  bf16x8 bfr[24];  // 0..7 x-part (K 0..255), 8..23 h-part (K 256..767)
#pragma unroll
  for (int kk = 0; kk < 24; ++kk) {
    int k0 = kk * 32 + hi8;
    bfr[kk] = cvt8(*(const float4*)(wrow + k0), *(const float4*)(wrow + k0 + 4));
  }
  const int hc_abs = s * 32 + wave * 4 + (lane & 3);
  const float bi_r = bi[hc_abs], bf_r = bfp[hc_abs], bg_r = bgp[hc_abs], bo_r = bop[hc_abs];

  // x pipeline: 2-step register lookahead
  float4 rx[2];
  auto ldx = [&](int t) {
    const float4* xs = (const float4*)(x + ((size_t)t * BATCH + g * 16) * IDIM);
    rx[0] = xs[tid];
    rx[1] = xs[tid + 512];
  };
  auto stx = [&](int par) {
#pragma unroll
    for (int j = 0; j < 2; ++j) {
      int i = tid + j * 512;
      int r = i >> 6, k4 = i & 63;
      float4 v = rx[j];
      ushort4 u;
      u.x = f2b(v.x); u.y = f2b(v.y); u.z = f2b(v.z); u.w = f2b(v.w);
      *(ushort4*)&xsl[par * XSLAB + r * LDX + k4 * 4] = u;
    }
  };

  // bootstrap: x(0) -> slab0 -> acc ; x(1) -> regs
  ldx(0);
  stx(0);
  __syncthreads();
  f32x4 c0 = {}, c1 = {};
  {
    const short* ax = &xsl[(lane & 15) * LDX + hi8];
#pragma unroll
    for (int kk = 0; kk < 8; kk += 2) {
      c0 = __builtin_amdgcn_mfma_f32_16x16x32_bf16(*(const bf16x8*)(ax + kk * 32),
                                                   bfr[kk], c0, 0, 0, 0);
      c1 = __builtin_amdgcn_mfma_f32_16x16x32_bf16(*(const bf16x8*)(ax + kk * 32 + 32),
                                                   bfr[kk + 1], c1, 0, 0, 0);
    }
  }
  ldx(1);

  float cst[4] = {0.f, 0.f, 0.f, 0.f};  // owner lanes: 4 rows x 1 h-col
  // replica line for (producer=lane, wave-slot=wave) within group g
  int* pollp = (lane < NSLOT)
                   ? flags + ((g * NSLOT + lane) * NREP + wave) * REP_STRIDE
                   : nullptr;
  int* pubbase = flags + ((g * NSLOT + s) * NREP) * REP_STRIDE;

  for (int t = 0; t < S_LEN; ++t) {
    // --- A: per-wave autonomous gather of the group's 16 flag replicas ---
    for (int it = 0; it < POLL_CAP; ++it) {
      int v = pollp ? l2_read(pollp) : 0x7fffffff;
      if (__all(v >= t)) break;
    }
    asm volatile("" ::: "memory");
    // --- B: h-part GEMM, A-frags DIRECT from L2 (no LDS, no barrier) ---
    {
      const short* hb = (const short*)h_all +
                        ((size_t)t * BATCH + g * 16 + (lane & 15)) * HDIM + hi8;
#pragma unroll
      for (int kk = 0; kk < 16; kk += 2) {
        bf16x8 a0 = *(const bf16x8*)(hb + kk * 32);
        bf16x8 a1 = *(const bf16x8*)(hb + kk * 32 + 32);
        c0 = __builtin_amdgcn_mfma_f32_16x16x32_bf16(a0, bfr[8 + kk], c0, 0, 0, 0);
        c1 = __builtin_amdgcn_mfma_f32_16x16x32_bf16(a1, bfr[9 + kk], c1, 0, 0, 0);
      }
    }
    // --- C: in-wave gate combine + state update + packed publish ---
    {
      f32x4 av;
#pragma unroll
      for (int j = 0; j < 4; ++j) av[j] = c0[j] + c1[j];
      const int row0 = (lane >> 4) * 4;
      u32t* hw_base = (u32t*)((short*)h_all + (size_t)(t + 1) * BATCH * HDIM);
#pragma unroll
      for (int j = 0; j < 4; ++j) {
        float iv = av[j];
        float fv = __shfl(av[j], lane + 4);
        float gv = __shfl(av[j], lane + 8);
        float ov = __shfl(av[j], lane + 12);
        if ((lane & 12) == 0) {  // 16 owner lanes: col q, rows row0..row0+3
          float ig = sigmoidf_(bi_r + iv);
          float fg = sigmoidf_(bf_r + fv);
          float gg = tanhf_(bg_r + gv);
          float og = sigmoidf_(bo_r + ov);
          cst[j] = fg * cst[j] + ig * gg;
          float hv = og * tanhf_(cst[j]);
          float hvp = __shfl_xor(hv, 1);  // col partner (owner lanes pair 0-1,2-3)
          if (!(lane & 1)) {
            u32t hw = (u32t)f2b(hv) | ((u32t)f2b(hvp) << 16);
            hw_base[((size_t)(g * 16 + row0 + j) * HDIM + hc_abs) >> 1] = hw;
          }
        }
      }
    }
    asm volatile("s_waitcnt vmcnt(0)" ::: "memory");  // h(t+1) acked at L2
    __syncthreads();                                  // whole block published
    if (tid < NREP)
      __hip_atomic_store(pubbase + tid * REP_STRIDE, t + 1, __ATOMIC_RELAXED,
                         __HIP_MEMORY_SCOPE_WORKGROUP);
    // --- D (shadow): x slab handoff + x-part GEMM for t+1 + x(t+2) loads ---
    if (t + 1 < S_LEN) {
      stx((t + 1) & 1);
      __syncthreads();
      f32x4 z = {};
      c0 = z;
      c1 = z;
      const short* ax = &xsl[((t + 1) & 1) * XSLAB + (lane & 15) * LDX + hi8];
#pragma unroll
      for (int kk = 0; kk < 8; kk += 2) {
        c0 = __builtin_amdgcn_mfma_f32_16x16x32_bf16(*(const bf16x8*)(ax + kk * 32),
                                                     bfr[kk], c0, 0, 0, 0);
        c1 = __builtin_amdgcn_mfma_f32_16x16x32_bf16(*(const bf16x8*)(ax + kk * 32 + 32),
                                                     bfr[kk + 1], c1, 0, 0, 0);
      }
      ldx((t + 2 < S_LEN) ? t + 2 : S_LEN - 1);
    }
  }
}

// ===== output projection + log-softmax: massively parallel, after the scan =====
__global__ __launch_bounds__(256) void lstm_out(
    const __hip_bfloat16* __restrict__ h_all,
    const __hip_bfloat16* __restrict__ wh2o_bf, const float* __restrict__ bh2o,
    float* __restrict__ out) {
  const int t = blockIdx.x;
  const int tid = threadIdx.x;
  const int lane = tid & 63;
  const int wave = tid >> 6;
  const int r0 = wave * 16;
  const short* abase = (const short*)h_all +
                       ((size_t)(t + 1) * BATCH + r0 + (lane & 15)) * HDIM + (lane >> 4) * 8;
  const short* bbase = (const short*)wh2o_bf + (size_t)(lane & 15) * HDIM + (lane >> 4) * 8;
  f32x4 acc[32];
  f32x4 zero = {0.f, 0.f, 0.f, 0.f};
#pragma unroll
  for (int n = 0; n < 32; ++n) acc[n] = zero;
  for (int kk = 0; kk < 16; ++kk) {
    bf16x8 a = *(const bf16x8*)(abase + kk * 32);
#pragma unroll
    for (int n = 0; n < 32; ++n) {
      bf16x8 b = *(const bf16x8*)(bbase + (size_t)n * 16 * HDIM + kk * 32);
      acc[n] = __builtin_amdgcn_mfma_f32_16x16x32_bf16(a, b, acc[n], 0, 0, 0);
    }
  }
  float mx[4] = {-3.0e38f, -3.0e38f, -3.0e38f, -3.0e38f};
#pragma unroll
  for (int n = 0; n < 32; ++n) {
    float bn = bh2o[n * 16 + (lane & 15)];
#pragma unroll
    for (int j = 0; j < 4; ++j) {
      acc[n][j] += bn;
      mx[j] = fmaxf(mx[j], acc[n][j]);
    }
  }
#pragma unroll
  for (int j = 0; j < 4; ++j) {
    mx[j] = fmaxf(mx[j], __shfl_xor(mx[j], 1));
    mx[j] = fmaxf(mx[j], __shfl_xor(mx[j], 2));
    mx[j] = fmaxf(mx[j], __shfl_xor(mx[j], 4));
    mx[j] = fmaxf(mx[j], __shfl_xor(mx[j], 8));
  }
  float sm[4] = {0.f, 0.f, 0.f, 0.f};
#pragma unroll
  for (int n = 0; n < 32; ++n) {
#pragma unroll
    for (int j = 0; j < 4; ++j) sm[j] += __expf(acc[n][j] - mx[j]);
  }
#pragma unroll
  for (int j = 0; j < 4; ++j) {
    sm[j] += __shfl_xor(sm[j], 1);
    sm[j] += __shfl_xor(sm[j], 2);
    sm[j] += __shfl_xor(sm[j], 4);
    sm[j] += __shfl_xor(sm[j], 8);
  }
  float ls[4];
#pragma unroll
  for (int j = 0; j < 4; ++j) ls[j] = mx[j] + __logf(sm[j]);
  float* ob = out + (size_t)t * BATCH * ODIM;
#pragma unroll
  for (int n = 0; n < 32; ++n) {
#pragma unroll
    for (int j = 0; j < 4; ++j) {
      int row = r0 + (lane >> 4) * 4 + j;
      ob[(size_t)row * ODIM + n * 16 + (lane & 15)] = acc[n][j] - ls[j];
    }
  }
}

extern "C" void kernel_launch(void* const* d_in, const int* in_sizes, int n_in,
                              void* d_out, int out_size, void* d_ws, size_t ws_size,
                              hipStream_t stream) {
  const float* x = (const float*)d_in[0];
  const float* Wi = (const float*)d_in[1];
  const float* bi = (const float*)d_in[2];
  const float* Wf = (const float*)d_in[3];
  const float* bf = (const float*)d_in[4];
  const float* Wg = (const float*)d_in[5];
  const float* bg = (const float*)d_in[6];
  const float* Wo = (const float*)d_in[7];
  const float* bo = (const float*)d_in[8];
  const float* Wh2o = (const float*)d_in[9];
  const float* bh2o = (const float*)d_in[10];

  char* ws = (char*)d_ws;
  int* cnt = (int*)ws;                 // 8 XCD counters (padded), < 4KB
  int* flags = (int*)(ws + 4096);      // [NGRP][NSLOT][NREP] 128B lines = 64KB
  __hip_bfloat16* h_all = (__hip_bfloat16*)(ws + 131072);  // [S+1][64][512]
  size_t h_all_b = (size_t)(S_LEN + 1) * BATCH * HDIM * 2;
  __hip_bfloat16* wh2o_bf = (__hip_bfloat16*)(ws + 131072 + h_all_b);
  size_t needed = 131072 + h_all_b + (size_t)ODIM * HDIM * 2;
  if (ws_size < needed || n_in < 11) return;

  hipFuncSetAttribute((const void*)lstm_recur,
                      hipFuncAttributeMaxDynamicSharedMemorySize, SMEM_BYTES);

  lstm_init<<<1024, 256, 0, stream>>>(Wh2o, wh2o_bf, h_all, (int*)ws);
  lstm_recur<<<256, 512, SMEM_BYTES, stream>>>(x, Wi, bi, Wf, bf, Wg, bg, Wo, bo,
                                               h_all, flags, cnt);
  lstm_out<<<S_LEN, 256, 0, stream>>>(h_all, wh2o_bf, bh2o, (float*)d_out);
}

// Round 13
// 12190.746 us; speedup vs baseline: 1.7109x; 1.3364x over previous
//
#include <hip/hip_runtime.h>
#include <hip/hip_bf16.h>

typedef __attribute__((ext_vector_type(8))) short bf16x8;
typedef __attribute__((ext_vector_type(4))) float f32x4;
typedef unsigned int u32t;

#define S_LEN 2048
#define BATCH 64
#define IDIM 256
#define HDIM 512
#define KDIM 768
#define ODIM 512
#define NGRP 4    // groups = XCDs 0..3, 16 batch rows each
#define NSLOT 32  // blocks per group, each owns 16 h-cols (R6 shape)
#define LDK 792   // comb row stride (shorts)
#define FLAG_PAD 16
#define POLL_CAP (1 << 16)

#define OFF_PRE (16 * LDK * 2)                    // comb [16][LDK] bf16 = 25344
#define OFF_BIAS (OFF_PRE + 2 * 4 * 16 * 17 * 4)  // pre [8][16][17] f32 -> 34048
#define OFF_CTL (OFF_BIAS + 256)                  // bias 64*4 -> 34304
#define SMEM_BYTES 98304                          // force 1 block/CU

__device__ __forceinline__ unsigned short f2b(float f) {
  __hip_bfloat16 h = __float2bfloat16(f);
  return __builtin_bit_cast(unsigned short, h);
}
__device__ __forceinline__ float sigmoidf_(float x) { return 1.0f / (1.0f + __expf(-x)); }
__device__ __forceinline__ float tanhf_(float x) { return 1.0f - 2.0f / (1.0f + __expf(2.0f * x)); }

__device__ __forceinline__ bf16x8 cvt8(float4 v0, float4 v1) {
  bf16x8 b;
  b[0] = (short)f2b(v0.x); b[1] = (short)f2b(v0.y);
  b[2] = (short)f2b(v0.z); b[3] = (short)f2b(v0.w);
  b[4] = (short)f2b(v1.x); b[5] = (short)f2b(v1.y);
  b[6] = (short)f2b(v1.z); b[7] = (short)f2b(v1.w);
  return b;
}

// Fresh L2 read: atomics execute at the XCD L2 (no L0 RMW path). HW-validated r6+.
__device__ __forceinline__ int l2_read(int* p) {
  int z = 0;
  asm volatile("" : "+v"(z));
  return __hip_atomic_fetch_add(p, z, __ATOMIC_RELAXED, __HIP_MEMORY_SCOPE_WORKGROUP);
}

// 8-worker-wave LDS barrier (burner waves never participate).
__device__ __forceinline__ void wbar(int* lbar, int target, int lane) {
  asm volatile("s_waitcnt lgkmcnt(0)" ::: "memory");  // my LDS writes visible
  if (lane == 0) atomicAdd(lbar, 1);
  while (__hip_atomic_load(lbar, __ATOMIC_RELAXED, __HIP_MEMORY_SCOPE_WORKGROUP) < target) {
  }
  asm volatile("" ::: "memory");
}

__global__ void lstm_init(const float* __restrict__ wh2o,
                          __hip_bfloat16* __restrict__ wh2o_bf,
                          __hip_bfloat16* __restrict__ h_all,
                          int* __restrict__ ctrl) {
  int idx = blockIdx.x * 256 + threadIdx.x;
  if (idx < ODIM * HDIM) wh2o_bf[idx] = __float2bfloat16(wh2o[idx]);
  if (idx < BATCH * HDIM) h_all[idx] = __float2bfloat16(0.0f);  // h(0) = 0
  if (idx < 16384) ctrl[idx] = 0;  // cnt + flags
}

// ===== persistent recurrence (R6 worker) + co-resident burner waves =====
__global__ __launch_bounds__(1024) void lstm_recur(
    const float* __restrict__ x,
    const float* __restrict__ Wi, const float* __restrict__ bi,
    const float* __restrict__ Wf, const float* __restrict__ bfp,
    const float* __restrict__ Wg, const float* __restrict__ bgp,
    const float* __restrict__ Wo, const float* __restrict__ bop,
    __hip_bfloat16* __restrict__ h_all, int* __restrict__ flags,
    int* __restrict__ cnt) {
  extern __shared__ char smem[];
  __shared__ int sel[2];
  const int tid = threadIdx.x;
  const int lane = tid & 63;
  const int wave = tid >> 6;
  int* lbar = (int*)(smem + OFF_CTL);
  int* ldone = (int*)(smem + OFF_CTL + 64);

  if (tid == 0) {
    unsigned xcd;
    asm("s_getreg_b32 %0, hwreg(HW_REG_XCC_ID)" : "=s"(xcd));
    sel[0] = (int)(xcd & 7);
    sel[1] = atomicAdd(&cnt[(xcd & 7) * 16], 1);  // one-time, device scope
    *lbar = 0;
    *ldone = 0;
  }
  __syncthreads();  // the ONLY full-block barrier
  const int g = sel[0];
  const int s = sel[1];
  if (g >= NGRP || s >= NSLOT) return;  // XCDs 4-7 + surplus exit

  if (wave >= 8) {
    // ===== burner: keep the CU's SIMDs busy so the SMU holds boost clocks =====
    f32x4 acc = {};
    bf16x8 za = {};
    for (int it = 0; it < (1 << 18); ++it) {
#pragma unroll
      for (int m = 0; m < 8; ++m)
        acc = __builtin_amdgcn_mfma_f32_16x16x32_bf16(za, za, acc, 0, 0, 0);
      asm volatile("" : "+v"(acc));  // keep alive (no DCE)
      if ((it & 7) == 7) {
        if (__hip_atomic_load(ldone, __ATOMIC_RELAXED, __HIP_MEMORY_SCOPE_WORKGROUP)) break;
      }
    }
    return;
  }

  // ===== worker waves 0..7: exact R6 structure, wbar instead of syncthreads =====
  __builtin_amdgcn_s_setprio(1);
  short* comb = (short*)smem;               // [16][LDK] bf16: x(0..255) | h(256..767)
  float* pre = (float*)(smem + OFF_PRE);    // [2][4][16][17] partial preacts
  float* blds = (float*)(smem + OFF_BIAS);  // [4][16]
  int bt = 0;

  const int ct = wave & 3;   // gate
  const int kh = wave >> 2;  // K-half (384 each: x128 + h256)
  const int rc16 = lane & 15;
  const int ksub = (lane >> 4) * 8;

  const float* wsrc = (ct == 0) ? Wi : (ct == 1) ? Wf : (ct == 2) ? Wg : Wo;
  const float* wrow = wsrc + (size_t)(s * 16 + rc16) * KDIM;
  bf16x8 bfx[4], bfh[8];
#pragma unroll
  for (int kk = 0; kk < 4; ++kk) {
    int k0 = kh * 128 + kk * 32 + ksub;
    bfx[kk] = cvt8(*(const float4*)(wrow + k0), *(const float4*)(wrow + k0 + 4));
  }
#pragma unroll
  for (int kk = 0; kk < 8; ++kk) {
    int k0 = IDIM + kh * 256 + kk * 32 + ksub;
    bfh[kk] = cvt8(*(const float4*)(wrow + k0), *(const float4*)(wrow + k0 + 4));
  }
  if (tid < 64) {
    int gate = tid >> 4;
    const float* bsrc = (gate == 0) ? bi : (gate == 1) ? bfp : (gate == 2) ? bgp : bop;
    blds[tid] = bsrc[s * 16 + (tid & 15)];
  }

  float4 rx[2];
  auto ldx = [&](int t) {
    const float4* xs = (const float4*)(x + ((size_t)t * BATCH + g * 16) * IDIM);
    rx[0] = xs[tid];
    rx[1] = xs[tid + 512];
  };
  auto stx = [&]() {
#pragma unroll
    for (int j = 0; j < 2; ++j) {
      int i = tid + j * 512;
      int r = i >> 6, k4 = i & 63;
      float4 v = rx[j];
      ushort4 u;
      u.x = f2b(v.x); u.y = f2b(v.y); u.z = f2b(v.z); u.w = f2b(v.w);
      *(ushort4*)&comb[r * LDK + k4 * 4] = u;
    }
  };

  const short* acx = &comb[rc16 * LDK + kh * 128 + ksub];
  const short* ach = &comb[rc16 * LDK + IDIM + kh * 256 + ksub];

  ldx(0);
  stx();
  bt += 8; wbar(lbar, bt, lane);
  f32x4 acc = {}, acc2 = {};
  acc = __builtin_amdgcn_mfma_f32_16x16x32_bf16(*(const bf16x8*)(acx + 0), bfx[0], acc, 0, 0, 0);
  acc2 = __builtin_amdgcn_mfma_f32_16x16x32_bf16(*(const bf16x8*)(acx + 32), bfx[1], acc2, 0, 0, 0);
  acc = __builtin_amdgcn_mfma_f32_16x16x32_bf16(*(const bf16x8*)(acx + 64), bfx[2], acc, 0, 0, 0);
  acc2 = __builtin_amdgcn_mfma_f32_16x16x32_bf16(*(const bf16x8*)(acx + 96), bfx[3], acc2, 0, 0, 0);
  ldx(1);

  float cst = 0.0f;
  const int gm = tid >> 4;  // gate row (tid<256)
  const int gn = tid & 15;  // gate h-col
  int* myflag = flags + (g * NSLOT + s) * FLAG_PAD;
  int* gflags = flags + g * NSLOT * FLAG_PAD;

  for (int t = 0; t < S_LEN; ++t) {
    // --- 1. wave0 polls all 32 group flags at the XCD L2 (capped) ---
    if (wave == 0) {
      for (int it = 0; it < POLL_CAP; ++it) {
        int v = (lane < NSLOT) ? l2_read(gflags + lane * FLAG_PAD) : 0x7fffffff;
        if (__all(v >= t)) break;
        __builtin_amdgcn_s_sleep(1);
      }
    }
    bt += 8; wbar(lbar, bt, lane);
    // --- 2. stage h(t) slab -> LDS (addresses new each step: L0-safe) ---
    {
      const short* hs = (const short*)h_all + ((size_t)t * BATCH + g * 16) * HDIM;
      int r = tid >> 5, c16 = tid & 31;
      const short* sp = hs + r * HDIM + c16 * 16;
      bf16x8 v0 = *(const bf16x8*)sp;
      bf16x8 v1 = *(const bf16x8*)(sp + 8);
      short* dp = &comb[r * LDK + IDIM + c16 * 16];
      *(bf16x8*)dp = v0;
      *(bf16x8*)(dp + 8) = v1;
    }
    bt += 8; wbar(lbar, bt, lane);
    // --- 3. h-part GEMM (2 interleaved chains) ---
#pragma unroll
    for (int kk = 0; kk < 8; kk += 2) {
      acc = __builtin_amdgcn_mfma_f32_16x16x32_bf16(*(const bf16x8*)(ach + kk * 32), bfh[kk],
                                                    acc, 0, 0, 0);
      acc2 = __builtin_amdgcn_mfma_f32_16x16x32_bf16(*(const bf16x8*)(ach + kk * 32 + 32),
                                                     bfh[kk + 1], acc2, 0, 0, 0);
    }
    // --- 4. exchange preacts across waves ---
#pragma unroll
    for (int j = 0; j < 4; ++j) {
      int m = (lane >> 4) * 4 + j;
      pre[((kh * 4 + ct) * 16 + m) * 17 + rc16] = acc[j] + acc2[j];
    }
    bt += 8; wbar(lbar, bt, lane);
    // --- 5. gates + state update + publish h(t+1) (WT stores -> L2) ---
    if (tid < 256) {
      float pi = blds[gn] + pre[(0 * 16 + gm) * 17 + gn] + pre[(4 * 16 + gm) * 17 + gn];
      float pf = blds[16 + gn] + pre[(1 * 16 + gm) * 17 + gn] + pre[(5 * 16 + gm) * 17 + gn];
      float pg = blds[32 + gn] + pre[(2 * 16 + gm) * 17 + gn] + pre[(6 * 16 + gm) * 17 + gn];
      float po = blds[48 + gn] + pre[(3 * 16 + gm) * 17 + gn] + pre[(7 * 16 + gm) * 17 + gn];
      float ig = sigmoidf_(pi), fg = sigmoidf_(pf), gv = tanhf_(pg), og = sigmoidf_(po);
      cst = fg * cst + ig * gv;
      float hv = og * tanhf_(cst);
      float hv2 = __shfl_xor(hv, 1);
      if ((gn & 1) == 0) {
        u32t hw = (u32t)f2b(hv) | ((u32t)f2b(hv2) << 16);
        u32t* dst = (u32t*)((short*)h_all +
                            ((size_t)(t + 1) * BATCH + g * 16 + gm) * HDIM + s * 16 + gn);
        *dst = hw;
      }
    }
    asm volatile("s_waitcnt vmcnt(0)" ::: "memory");  // h(t+1) acked at L2
    bt += 8; wbar(lbar, bt, lane);
    if (tid == 0)
      __hip_atomic_store(myflag, t + 1, __ATOMIC_RELAXED, __HIP_MEMORY_SCOPE_WORKGROUP);
    // --- 6. x pipeline in the publish shadow ---
    if (t + 1 < S_LEN) {
      stx();
      bt += 8; wbar(lbar, bt, lane);
      f32x4 z = {};
      acc = z;
      acc2 = z;
      acc = __builtin_amdgcn_mfma_f32_16x16x32_bf16(*(const bf16x8*)(acx + 0), bfx[0], acc, 0, 0, 0);
      acc2 = __builtin_amdgcn_mfma_f32_16x16x32_bf16(*(const bf16x8*)(acx + 32), bfx[1], acc2, 0, 0, 0);
      acc = __builtin_amdgcn_mfma_f32_16x16x32_bf16(*(const bf16x8*)(acx + 64), bfx[2], acc, 0, 0, 0);
      acc2 = __builtin_amdgcn_mfma_f32_16x16x32_bf16(*(const bf16x8*)(acx + 96), bfx[3], acc2, 0, 0, 0);
      ldx((t + 2 < S_LEN) ? t + 2 : S_LEN - 1);
    }
  }
  if (tid == 0)
    __hip_atomic_store(ldone, 1, __ATOMIC_RELAXED, __HIP_MEMORY_SCOPE_WORKGROUP);
}

// ===== output projection + log-softmax: massively parallel, after the scan =====
__global__ __launch_bounds__(256) void lstm_out(
    const __hip_bfloat16* __restrict__ h_all,
    const __hip_bfloat16* __restrict__ wh2o_bf, const float* __restrict__ bh2o,
    float* __restrict__ out) {
  const int t = blockIdx.x;
  const int tid = threadIdx.x;
  const int lane = tid & 63;
  const int wave = tid >> 6;
  const int r0 = wave * 16;
  const short* abase = (const short*)h_all +
                       ((size_t)(t + 1) * BATCH + r0 + (lane & 15)) * HDIM + (lane >> 4) * 8;
  const short* bbase = (const short*)wh2o_bf + (size_t)(lane & 15) * HDIM + (lane >> 4) * 8;
  f32x4 acc[32];
  f32x4 zero = {0.f, 0.f, 0.f, 0.f};
#pragma unroll
  for (int n = 0; n < 32; ++n) acc[n] = zero;
  for (int kk = 0; kk < 16; ++kk) {
    bf16x8 a = *(const bf16x8*)(abase + kk * 32);
#pragma unroll
    for (int n = 0; n < 32; ++n) {
      bf16x8 b = *(const bf16x8*)(bbase + (size_t)n * 16 * HDIM + kk * 32);
      acc[n] = __builtin_amdgcn_mfma_f32_16x16x32_bf16(a, b, acc[n], 0, 0, 0);
    }
  }
  float mx[4] = {-3.0e38f, -3.0e38f, -3.0e38f, -3.0e38f};
#pragma unroll
  for (int n = 0; n < 32; ++n) {
    float bn = bh2o[n * 16 + (lane & 15)];
#pragma unroll
    for (int j = 0; j < 4; ++j) {
      acc[n][j] += bn;
      mx[j] = fmaxf(mx[j], acc[n][j]);
    }
  }
#pragma unroll
  for (int j = 0; j < 4; ++j) {
    mx[j] = fmaxf(mx[j], __shfl_xor(mx[j], 1));
    mx[j] = fmaxf(mx[j], __shfl_xor(mx[j], 2));
    mx[j] = fmaxf(mx[j], __shfl_xor(mx[j], 4));
    mx[j] = fmaxf(mx[j], __shfl_xor(mx[j], 8));
  }
  float sm[4] = {0.f, 0.f, 0.f, 0.f};
#pragma unroll
  for (int n = 0; n < 32; ++n) {
#pragma unroll
    for (int j = 0; j < 4; ++j) sm[j] += __expf(acc[n][j] - mx[j]);
  }
#pragma unroll
  for (int j = 0; j < 4; ++j) {
    sm[j] += __shfl_xor(sm[j], 1);
    sm[j] += __shfl_xor(sm[j], 2);
    sm[j] += __shfl_xor(sm[j], 4);
    sm[j] += __shfl_xor(sm[j], 8);
  }
  float ls[4];
#pragma unroll
  for (int j = 0; j < 4; ++j) ls[j] = mx[j] + __logf(sm[j]);
  float* ob = out + (size_t)t * BATCH * ODIM;
#pragma unroll
  for (int n = 0; n < 32; ++n) {
#pragma unroll
    for (int j = 0; j < 4; ++j) {
      int row = r0 + (lane >> 4) * 4 + j;
      ob[(size_t)row * ODIM + n * 16 + (lane & 15)] = acc[n][j] - ls[j];
    }
  }
}

extern "C" void kernel_launch(void* const* d_in, const int* in_sizes, int n_in,
                              void* d_out, int out_size, void* d_ws, size_t ws_size,
                              hipStream_t stream) {
  const float* x = (const float*)d_in[0];
  const float* Wi = (const float*)d_in[1];
  const float* bi = (const float*)d_in[2];
  const float* Wf = (const float*)d_in[3];
  const float* bf = (const float*)d_in[4];
  const float* Wg = (const float*)d_in[5];
  const float* bg = (const float*)d_in[6];
  const float* Wo = (const float*)d_in[7];
  const float* bo = (const float*)d_in[8];
  const float* Wh2o = (const float*)d_in[9];
  const float* bh2o = (const float*)d_in[10];

  char* ws = (char*)d_ws;
  int* cnt = (int*)ws;                    // 8 XCD counters (padded)
  int* flags = (int*)(ws + 4096);         // [NGRP][NSLOT][FLAG_PAD] ints
  __hip_bfloat16* h_all = (__hip_bfloat16*)(ws + 65536);  // [S+1][64][512]
  size_t h_all_b = (size_t)(S_LEN + 1) * BATCH * HDIM * 2;
  __hip_bfloat16* wh2o_bf = (__hip_bfloat16*)(ws + 65536 + h_all_b);
  size_t needed = 65536 + h_all_b + (size_t)ODIM * HDIM * 2;
  if (ws_size < needed || n_in < 11) return;

  hipFuncSetAttribute((const void*)lstm_recur,
                      hipFuncAttributeMaxDynamicSharedMemorySize, SMEM_BYTES);

  lstm_init<<<1024, 256, 0, stream>>>(Wh2o, wh2o_bf, h_all, (int*)ws);
  lstm_recur<<<256, 1024, SMEM_BYTES, stream>>>(x, Wi, bi, Wf, bf, Wg, bg, Wo, bo,
                                                h_all, flags, cnt);
  lstm_out<<<S_LEN, 256, 0, stream>>>(h_all, wh2o_bf, bh2o, (float*)d_out);
}

// Round 14
// 12151.458 us; speedup vs baseline: 1.7164x; 1.0032x over previous
//
#include <hip/hip_runtime.h>
#include <hip/hip_bf16.h>

typedef __attribute__((ext_vector_type(8))) short bf16x8;
typedef __attribute__((ext_vector_type(4))) float f32x4;
typedef unsigned int u32t;

#define S_LEN 2048
#define BATCH 64
#define IDIM 256
#define HDIM 512
#define KDIM 768
#define ODIM 512
#define NGRP 4    // groups = XCDs 0..3, 16 batch rows each
#define NSLOT 32  // blocks per group, each owns 16 h-cols (4 waves x 4)
#define NREP 4    // flag replicas: one per wave-slot
#define LDX 264   // x slab row stride (shorts)
#define XSLAB (16 * LDX)
#define REP_STRIDE 32     // ints per replica line (128B)
#define POLL_CAP (1 << 16)

#define SMEM_BYTES 98304  // force 1 block/CU (placement determinism)

__device__ __forceinline__ unsigned short f2b(float f) {
  __hip_bfloat16 h = __float2bfloat16(f);
  return __builtin_bit_cast(unsigned short, h);
}
__device__ __forceinline__ float sigmoidf_(float x) { return 1.0f / (1.0f + __expf(-x)); }
__device__ __forceinline__ float tanhf_(float x) { return 1.0f - 2.0f / (1.0f + __expf(2.0f * x)); }

__device__ __forceinline__ bf16x8 cvt8(float4 v0, float4 v1) {
  bf16x8 b;
  b[0] = (short)f2b(v0.x); b[1] = (short)f2b(v0.y);
  b[2] = (short)f2b(v0.z); b[3] = (short)f2b(v0.w);
  b[4] = (short)f2b(v1.x); b[5] = (short)f2b(v1.y);
  b[6] = (short)f2b(v1.z); b[7] = (short)f2b(v1.w);
  return b;
}

// Fresh L2 read: atomics execute at the XCD L2 (no L0 RMW path). Opaque addend
// stops LLVM folding fetch_add(p,0) into a cacheable load. HW-validated r6-r13.
__device__ __forceinline__ int l2_read(int* p) {
  int z = 0;
  asm volatile("" : "+v"(z));
  return __hip_atomic_fetch_add(p, z, __ATOMIC_RELAXED, __HIP_MEMORY_SCOPE_WORKGROUP);
}

__global__ void lstm_init(const float* __restrict__ wh2o,
                          __hip_bfloat16* __restrict__ wh2o_bf,
                          __hip_bfloat16* __restrict__ h_all,
                          int* __restrict__ ctrl) {
  int idx = blockIdx.x * 256 + threadIdx.x;
  if (idx < ODIM * HDIM) wh2o_bf[idx] = __float2bfloat16(wh2o[idx]);
  if (idx < BATCH * HDIM) h_all[idx] = __float2bfloat16(0.0f);  // h(0) = 0
  if (idx < 32768) ctrl[idx] = 0;  // cnt + replicated flags (128KB)
}

// ===== persistent recurrence: 4 XCD-local groups, 32 blocks x 256 threads =====
__global__ __launch_bounds__(256) void lstm_recur(
    const float* __restrict__ x,
    const float* __restrict__ Wi, const float* __restrict__ bi,
    const float* __restrict__ Wf, const float* __restrict__ bfp,
    const float* __restrict__ Wg, const float* __restrict__ bgp,
    const float* __restrict__ Wo, const float* __restrict__ bop,
    __hip_bfloat16* __restrict__ h_all, int* __restrict__ flags,
    int* __restrict__ cnt) {
  extern __shared__ char smem[];
  __shared__ int sel[2];
  const int tid = threadIdx.x;
  const int lane = tid & 63;
  const int wave = tid >> 6;  // 0..3

  if (tid == 0) {
    unsigned xcd;
    asm("s_getreg_b32 %0, hwreg(HW_REG_XCC_ID)" : "=s"(xcd));
    sel[0] = (int)(xcd & 7);
    sel[1] = atomicAdd(&cnt[(xcd & 7) * 16], 1);  // one-time, device scope
  }
  __syncthreads();
  const int g = sel[0];
  const int s = sel[1];
  if (g >= NGRP || s >= NSLOT) return;  // XCDs 4-7 + surplus blocks idle

  short* xsl = (short*)smem;  // [2][16][LDX] bf16 (only LDS use)

  // Wave's MFMA B-tile: 16 cols = {gate 0..3} x {h-col wave*4+q}, full K=768.
  const int bc = lane & 15;
  const int gate = bc >> 2;
  const int q = bc & 3;
  const int hi8 = (lane >> 4) * 8;  // K sub-slice

  // --- prologue: weight fragments fp32 -> bf16 registers ---
  const float* wsrc = (gate == 0) ? Wi : (gate == 1) ? Wf : (gate == 2) ? Wg : Wo;
  const float* wrow = wsrc + (size_t)(s * 16 + wave * 4 + q) * KDIM;
  bf16x8 bfr[24];  // 0..7 x-part (K 0..255), 8..23 h-part (K 256..767)
#pragma unroll
  for (int kk = 0; kk < 8; ++kk) {
    int k0 = kk * 32 + hi8;
    bfr[kk] = cvt8(*(const float4*)(wrow + k0), *(const float4*)(wrow + k0 + 4));
  }
#pragma unroll
  for (int kk = 8; kk < 24; ++kk) {
    int k0 = IDIM + (kk - 8) * 32 + hi8;
    bfr[kk] = cvt8(*(const float4*)(wrow + k0), *(const float4*)(wrow + k0 + 4));
  }
  const int hc_abs = s * 16 + wave * 4 + (lane & 3);
  const float bi_r = bi[hc_abs], bf_r = bfp[hc_abs], bg_r = bgp[hc_abs], bo_r = bop[hc_abs];

  // x pipeline: 2-step register lookahead (4 float4/thread at 256 threads)
  float4 rx[4];
  auto ldx = [&](int t) {
    const float4* xs = (const float4*)(x + ((size_t)t * BATCH + g * 16) * IDIM);
#pragma unroll
    for (int j = 0; j < 4; ++j) rx[j] = xs[tid + j * 256];
  };
  auto stx = [&](int par) {
#pragma unroll
    for (int j = 0; j < 4; ++j) {
      int i = tid + j * 256;
      int r = i >> 6, k4 = i & 63;
      float4 v = rx[j];
      ushort4 u;
      u.x = f2b(v.x); u.y = f2b(v.y); u.z = f2b(v.z); u.w = f2b(v.w);
      *(ushort4*)&xsl[par * XSLAB + r * LDX + k4 * 4] = u;
    }
  };

  // bootstrap: x(0) -> slab0 -> acc ; x(1) -> regs
  ldx(0);
  stx(0);
  __syncthreads();
  f32x4 c0 = {}, c1 = {};
  {
    const short* ax = &xsl[(lane & 15) * LDX + hi8];
#pragma unroll
    for (int kk = 0; kk < 8; kk += 2) {
      c0 = __builtin_amdgcn_mfma_f32_16x16x32_bf16(*(const bf16x8*)(ax + kk * 32),
                                                   bfr[kk], c0, 0, 0, 0);
      c1 = __builtin_amdgcn_mfma_f32_16x16x32_bf16(*(const bf16x8*)(ax + kk * 32 + 32),
                                                   bfr[kk + 1], c1, 0, 0, 0);
    }
  }
  ldx(1);

  float cst[4] = {0.f, 0.f, 0.f, 0.f};  // owner lanes: 4 rows x 1 h-col
  int* pollp = (lane < NSLOT)
                   ? flags + ((g * NSLOT + lane) * NREP + wave) * REP_STRIDE
                   : nullptr;
  int* pubbase = flags + ((g * NSLOT + s) * NREP) * REP_STRIDE;

  for (int t = 0; t < S_LEN; ++t) {
    // --- A: per-wave gather of the group's 32 flag replicas (no sleep) ---
    for (int it = 0; it < POLL_CAP; ++it) {
      int v = pollp ? l2_read(pollp) : 0x7fffffff;
      if (__all(v >= t)) break;
    }
    asm volatile("" ::: "memory");
    // --- B: h-part GEMM, A-frags DIRECT from L2 (no LDS, no barrier) ---
    {
      const short* hb = (const short*)h_all +
                        ((size_t)t * BATCH + g * 16 + (lane & 15)) * HDIM + hi8;
#pragma unroll
      for (int kk = 0; kk < 16; kk += 2) {
        bf16x8 a0 = *(const bf16x8*)(hb + kk * 32);
        bf16x8 a1 = *(const bf16x8*)(hb + kk * 32 + 32);
        c0 = __builtin_amdgcn_mfma_f32_16x16x32_bf16(a0, bfr[8 + kk], c0, 0, 0, 0);
        c1 = __builtin_amdgcn_mfma_f32_16x16x32_bf16(a1, bfr[9 + kk], c1, 0, 0, 0);
      }
    }
    // --- C: in-wave gate combine + state update + packed publish ---
    {
      f32x4 av;
#pragma unroll
      for (int j = 0; j < 4; ++j) av[j] = c0[j] + c1[j];
      const int row0 = (lane >> 4) * 4;
      u32t* hw_base = (u32t*)((short*)h_all + (size_t)(t + 1) * BATCH * HDIM);
#pragma unroll
      for (int j = 0; j < 4; ++j) {
        float iv = av[j];
        float fv = __shfl(av[j], lane + 4);
        float gv = __shfl(av[j], lane + 8);
        float ov = __shfl(av[j], lane + 12);
        if ((lane & 12) == 0) {  // 16 owner lanes: col q, rows row0..row0+3
          float ig = sigmoidf_(bi_r + iv);
          float fg = sigmoidf_(bf_r + fv);
          float gg = tanhf_(bg_r + gv);
          float og = sigmoidf_(bo_r + ov);
          cst[j] = fg * cst[j] + ig * gg;
          float hv = og * tanhf_(cst[j]);
          float hvp = __shfl_xor(hv, 1);  // col partner (owner pairs 0-1, 2-3)
          if (!(lane & 1)) {
            u32t hw = (u32t)f2b(hv) | ((u32t)f2b(hvp) << 16);
            hw_base[((size_t)(g * 16 + row0 + j) * HDIM + hc_abs) >> 1] = hw;
          }
        }
      }
    }
    asm volatile("s_waitcnt vmcnt(0)" ::: "memory");  // h(t+1) acked at L2
    __syncthreads();                                  // whole block published
    if (tid < NREP)
      __hip_atomic_store(pubbase + tid * REP_STRIDE, t + 1, __ATOMIC_RELAXED,
                         __HIP_MEMORY_SCOPE_WORKGROUP);
    // --- D (shadow): x slab handoff + x-part GEMM for t+1 + x(t+2) loads ---
    if (t + 1 < S_LEN) {
      stx((t + 1) & 1);
      __syncthreads();
      f32x4 z = {};
      c0 = z;
      c1 = z;
      const short* ax = &xsl[((t + 1) & 1) * XSLAB + (lane & 15) * LDX + hi8];
#pragma unroll
      for (int kk = 0; kk < 8; kk += 2) {
        c0 = __builtin_amdgcn_mfma_f32_16x16x32_bf16(*(const bf16x8*)(ax + kk * 32),
                                                     bfr[kk], c0, 0, 0, 0);
        c1 = __builtin_amdgcn_mfma_f32_16x16x32_bf16(*(const bf16x8*)(ax + kk * 32 + 32),
                                                     bfr[kk + 1], c1, 0, 0, 0);
      }
      ldx((t + 2 < S_LEN) ? t + 2 : S_LEN - 1);
    }
  }
}

// ===== output projection + log-softmax: massively parallel, after the scan =====
__global__ __launch_bounds__(256) void lstm_out(
    const __hip_bfloat16* __restrict__ h_all,
    const __hip_bfloat16* __restrict__ wh2o_bf, const float* __restrict__ bh2o,
    float* __restrict__ out) {
  const int t = blockIdx.x;
  const int tid = threadIdx.x;
  const int lane = tid & 63;
  const int wave = tid >> 6;
  const int r0 = wave * 16;
  const short* abase = (const short*)h_all +
                       ((size_t)(t + 1) * BATCH + r0 + (lane & 15)) * HDIM + (lane >> 4) * 8;
  const short* bbase = (const short*)wh2o_bf + (size_t)(lane & 15) * HDIM + (lane >> 4) * 8;
  f32x4 acc[32];
  f32x4 zero = {0.f, 0.f, 0.f, 0.f};
#pragma unroll
  for (int n = 0; n < 32; ++n) acc[n] = zero;
  for (int kk = 0; kk < 16; ++kk) {
    bf16x8 a = *(const bf16x8*)(abase + kk * 32);
#pragma unroll
    for (int n = 0; n < 32; ++n) {
      bf16x8 b = *(const bf16x8*)(bbase + (size_t)n * 16 * HDIM + kk * 32);
      acc[n] = __builtin_amdgcn_mfma_f32_16x16x32_bf16(a, b, acc[n], 0, 0, 0);
    }
  }
  float mx[4] = {-3.0e38f, -3.0e38f, -3.0e38f, -3.0e38f};
#pragma unroll
  for (int n = 0; n < 32; ++n) {
    float bn = bh2o[n * 16 + (lane & 15)];
#pragma unroll
    for (int j = 0; j < 4; ++j) {
      acc[n][j] += bn;
      mx[j] = fmaxf(mx[j], acc[n][j]);
    }
  }
#pragma unroll
  for (int j = 0; j < 4; ++j) {
    mx[j] = fmaxf(mx[j], __shfl_xor(mx[j], 1));
    mx[j] = fmaxf(mx[j], __shfl_xor(mx[j], 2));
    mx[j] = fmaxf(mx[j], __shfl_xor(mx[j], 4));
    mx[j] = fmaxf(mx[j], __shfl_xor(mx[j], 8));
  }
  float sm[4] = {0.f, 0.f, 0.f, 0.f};
#pragma unroll
  for (int n = 0; n < 32; ++n) {
#pragma unroll
    for (int j = 0; j < 4; ++j) sm[j] += __expf(acc[n][j] - mx[j]);
  }
#pragma unroll
  for (int j = 0; j < 4; ++j) {
    sm[j] += __shfl_xor(sm[j], 1);
    sm[j] += __shfl_xor(sm[j], 2);
    sm[j] += __shfl_xor(sm[j], 4);
    sm[j] += __shfl_xor(sm[j], 8);
  }
  float ls[4];
#pragma unroll
  for (int j = 0; j < 4; ++j) ls[j] = mx[j] + __logf(sm[j]);
  float* ob = out + (size_t)t * BATCH * ODIM;
#pragma unroll
  for (int n = 0; n < 32; ++n) {
#pragma unroll
    for (int j = 0; j < 4; ++j) {
      int row = r0 + (lane >> 4) * 4 + j;
      ob[(size_t)row * ODIM + n * 16 + (lane & 15)] = acc[n][j] - ls[j];
    }
  }
}

extern "C" void kernel_launch(void* const* d_in, const int* in_sizes, int n_in,
                              void* d_out, int out_size, void* d_ws, size_t ws_size,
                              hipStream_t stream) {
  const float* x = (const float*)d_in[0];
  const float* Wi = (const float*)d_in[1];
  const float* bi = (const float*)d_in[2];
  const float* Wf = (const float*)d_in[3];
  const float* bf = (const float*)d_in[4];
  const float* Wg = (const float*)d_in[5];
  const float* bg = (const float*)d_in[6];
  const float* Wo = (const float*)d_in[7];
  const float* bo = (const float*)d_in[8];
  const float* Wh2o = (const float*)d_in[9];
  const float* bh2o = (const float*)d_in[10];

  char* ws = (char*)d_ws;
  int* cnt = (int*)ws;                 // 8 XCD counters (padded), < 4KB
  int* flags = (int*)(ws + 4096);      // [NGRP][NSLOT][NREP] 128B lines = 64KB
  __hip_bfloat16* h_all = (__hip_bfloat16*)(ws + 131072);  // [S+1][64][512]
  size_t h_all_b = (size_t)(S_LEN + 1) * BATCH * HDIM * 2;
  __hip_bfloat16* wh2o_bf = (__hip_bfloat16*)(ws + 131072 + h_all_b);
  size_t needed = 131072 + h_all_b + (size_t)ODIM * HDIM * 2;
  if (ws_size < needed || n_in < 11) return;

  hipFuncSetAttribute((const void*)lstm_recur,
                      hipFuncAttributeMaxDynamicSharedMemorySize, SMEM_BYTES);

  lstm_init<<<1024, 256, 0, stream>>>(Wh2o, wh2o_bf, h_all, (int*)ws);
  lstm_recur<<<256, 256, SMEM_BYTES, stream>>>(x, Wi, bi, Wf, bf, Wg, bg, Wo, bo,
                                               h_all, flags, cnt);
  lstm_out<<<S_LEN, 256, 0, stream>>>(h_all, wh2o_bf, bh2o, (float*)d_out);
}